// Round 8
// baseline (315.666 us; speedup 1.0000x reference)
//
#include <hip/hip_runtime.h>
#include <hip/hip_fp16.h>

// GCN: 100K nodes, 2.5M edges, dims 4 -> 32 -> (32x32 conv x3) -> 3.
// Round 8 (= R7 with compile fix): src-partitioned two-phase gather +
// NON-TEMPORAL hints on all streaming traffic (csr_src loads, Spart
// store/load, ei/x loads). The nontemporal builtins need clang native vector
// types, not HIP_vector_type -> use ext_vector_type(4) float and bit-cast.
// Build stays atomic-free; g fp16; accumulate fp32.

constexpr int N_NODES = 100000;
constexpr int N_EDGES = 2500000;
constexpr int HALFN   = 50000;
constexpr int BUCKET  = 256;
constexpr int NBUCK   = (N_NODES + BUCKET - 1) / BUCKET;   // 391
constexpr int NBLK    = 256;
constexpr int CHUNK   = (N_EDGES + NBLK - 1) / NBLK;       // 9766

typedef float vfloat4 __attribute__((ext_vector_type(4)));

__device__ inline int nt_ld(const int* p) { return __builtin_nontemporal_load(p); }
__device__ inline float4 nt_ld4(const float* p) {
    vfloat4 v = __builtin_nontemporal_load((const vfloat4*)p);
    return make_float4(v.x, v.y, v.z, v.w);
}
__device__ inline void nt_st4(float* p, float4 v) {
    vfloat4 w = {v.x, v.y, v.z, v.w};
    __builtin_nontemporal_store(w, (vfloat4*)p);
}

// ================= build =================
__global__ __launch_bounds__(256) void k_bincount(const int* __restrict__ ei,
                                                  int* __restrict__ blkbin) {
    __shared__ int hist[NBUCK];
    for (int i = threadIdx.x; i < NBUCK; i += 256) hist[i] = 0;
    __syncthreads();
    int beg = blockIdx.x * CHUNK;
    int end = min(beg + CHUNK, N_EDGES);
    for (int e = beg + threadIdx.x; e < end; e += 256) {
        int d = nt_ld(ei + N_EDGES + e);
        atomicAdd(&hist[d >> 8], 1);
    }
    __syncthreads();
    for (int i = threadIdx.x; i < NBUCK; i += 256)
        blkbin[i * NBLK + blockIdx.x] = hist[i];
}

__global__ __launch_bounds__(256) void k_bintot(const int* __restrict__ blkbin,
                                                int* __restrict__ bintot) {
    int w = threadIdx.x >> 6, lane = threadIdx.x & 63;
    int bin = blockIdx.x * 4 + w;
    if (bin >= NBUCK) return;
    int s = 0;
    for (int k = lane; k < NBLK; k += 64) s += blkbin[bin * NBLK + k];
#pragma unroll
    for (int o = 32; o > 0; o >>= 1) s += __shfl_down(s, o);
    if (lane == 0) bintot[bin] = s;
}

__global__ __launch_bounds__(512) void k_binscan(const int* __restrict__ bintot,
                                                 int* __restrict__ binoff) {
    __shared__ int sc[512];
    int tid = threadIdx.x;
    int v = (tid < NBUCK) ? bintot[tid] : 0;
    sc[tid] = v;
    __syncthreads();
#pragma unroll
    for (int o = 1; o < 512; o <<= 1) {
        int t = (tid >= o) ? sc[tid - o] : 0;
        __syncthreads();
        sc[tid] += t;
        __syncthreads();
    }
    if (tid < NBUCK) binoff[tid] = sc[tid] - v;
    if (tid == NBUCK - 1) binoff[NBUCK] = sc[tid];
}

__global__ __launch_bounds__(256) void k_blkoff(const int* __restrict__ blkbin,
                                                const int* __restrict__ binoff,
                                                int* __restrict__ blkoff) {
    int w = threadIdx.x >> 6, lane = threadIdx.x & 63;
    int bin = blockIdx.x * 4 + w;
    if (bin >= NBUCK) return;
    int v[4];
#pragma unroll
    for (int i = 0; i < 4; ++i) v[i] = blkbin[bin * NBLK + lane * 4 + i];
    int mysum = v[0] + v[1] + v[2] + v[3];
    int pre = mysum;
#pragma unroll
    for (int o = 1; o < 64; o <<= 1) {
        int t = __shfl_up(pre, o);
        if (lane >= o) pre += t;
    }
    pre -= mysum;
    int run = binoff[bin] + pre;
#pragma unroll
    for (int i = 0; i < 4; ++i) {
        blkoff[bin * NBLK + lane * 4 + i] = run;
        run += v[i];
    }
}

__global__ __launch_bounds__(256) void k_binfill(const int* __restrict__ ei,
                                                 const int* __restrict__ blkoff,
                                                 int* __restrict__ binned) {
    __shared__ int cur[NBUCK];
    for (int i = threadIdx.x; i < NBUCK; i += 256)
        cur[i] = blkoff[i * NBLK + blockIdx.x];
    __syncthreads();
    int beg = blockIdx.x * CHUNK;
    int end = min(beg + CHUNK, N_EDGES);
    for (int e = beg + threadIdx.x; e < end; e += 256) {
        int s = nt_ld(ei + e);
        int d = nt_ld(ei + N_EDGES + e);
        int pos = atomicAdd(&cur[d >> 8], 1);
        binned[pos] = (s << 8) | (d & 255);
    }
}

// ---- within-bucket counting sort, key = dst_local*2 + (src>=HALFN) ----
__global__ __launch_bounds__(512) void k_sortdeg(const int* __restrict__ binned,
                                                 const int* __restrict__ binoff,
                                                 int* __restrict__ csr_src,
                                                 int* __restrict__ rowptr,
                                                 int* __restrict__ rowmid,
                                                 float* __restrict__ dinv) {
    __shared__ int cnt[512];
    __shared__ int sc[512];
    __shared__ int cur[512];
    int t = threadIdx.x;
    int b = blockIdx.x;
    int beg = binoff[b], end = binoff[b + 1];

    cnt[t] = 0;
    __syncthreads();
    for (int k = beg + t; k < end; k += 512) {
        int p = binned[k];
        int key = ((p & 255) << 1) | (((p >> 8) >= HALFN) ? 1 : 0);
        atomicAdd(&cnt[key], 1);
    }
    __syncthreads();

    int v = cnt[t];
    sc[t] = v;
    __syncthreads();
#pragma unroll
    for (int o = 1; o < 512; o <<= 1) {
        int tv = (t >= o) ? sc[t - o] : 0;
        __syncthreads();
        sc[t] += tv;
        __syncthreads();
    }
    int excl = sc[t] - v;
    cur[t] = excl;
    int dl = t >> 1;
    int n = b * 256 + dl;
    if (n < N_NODES) {
        if ((t & 1) == 0) {
            rowptr[n] = beg + excl;
            dinv[n] = rsqrtf((float)(cnt[t] + cnt[t + 1] + 1));  // +1 self-loop
        } else {
            rowmid[n] = beg + excl;
        }
    }
    if (b == NBUCK - 1 && t == 0) rowptr[N_NODES] = end;
    __syncthreads();

    for (int k = beg + t; k < end; k += 512) {
        int p = binned[k];
        int key = ((p & 255) << 1) | (((p >> 8) >= HALFN) ? 1 : 0);
        int pos = atomicAdd(&cur[key], 1);
        csr_src[beg + pos] = p >> 8;
    }
}

// ================= dense helpers =================
__device__ inline void store_half8(__half* p, const float* v) {
    __half2 h[4];
#pragma unroll
    for (int i = 0; i < 4; ++i)
        h[i] = __floats2half2_rn(v[2 * i], v[2 * i + 1]);
    *(float4*)p = *(float4*)h;
}

__device__ inline void acc_half8(float* acc, float4 raw) {
    __half2* hp = (__half2*)&raw;
#pragma unroll
    for (int i = 0; i < 4; ++i) {
        float2 f = __half22float2(hp[i]);
        acc[2 * i]     += f.x;
        acc[2 * i + 1] += f.y;
    }
}

// t = relu(x@Wfc1 + bfc1); g = half( dinv * (t@Wc1) )
__global__ __launch_bounds__(256) void k_fc1_conv1(
        const float* __restrict__ x,
        const float* __restrict__ Wfc1, const float* __restrict__ bfc1,
        const float* __restrict__ Wc1, const float* __restrict__ dinv,
        __half* __restrict__ g) {
    __shared__ float  sWf[128];
    __shared__ float  sbf[32];
    __shared__ float4 sW[256];
    if (threadIdx.x < 128) sWf[threadIdx.x] = Wfc1[threadIdx.x];
    if (threadIdx.x < 32)  sbf[threadIdx.x] = bfc1[threadIdx.x];
    sW[threadIdx.x] = ((const float4*)Wc1)[threadIdx.x];
    __syncthreads();

    int n = blockIdx.x * 256 + threadIdx.x;
    if (n >= N_NODES) return;

    float4 xin = nt_ld4(x + (size_t)n * 4);
    float t[32];
#pragma unroll
    for (int j = 0; j < 32; ++j) {
        float a = fmaf(xin.x, sWf[j], sbf[j]);
        a = fmaf(xin.y, sWf[32 + j], a);
        a = fmaf(xin.z, sWf[64 + j], a);
        a = fmaf(xin.w, sWf[96 + j], a);
        t[j] = fmaxf(a, 0.0f);
    }
    float o[32];
#pragma unroll
    for (int j = 0; j < 32; ++j) o[j] = 0.f;
#pragma unroll
    for (int k = 0; k < 32; ++k) {
        float a = t[k];
#pragma unroll
        for (int q = 0; q < 8; ++q) {
            float4 w = sW[k * 8 + q];
            o[q * 4 + 0] = fmaf(a, w.x, o[q * 4 + 0]);
            o[q * 4 + 1] = fmaf(a, w.y, o[q * 4 + 1]);
            o[q * 4 + 2] = fmaf(a, w.z, o[q * 4 + 2]);
            o[q * 4 + 3] = fmaf(a, w.w, o[q * 4 + 3]);
        }
    }
    float dv = dinv[n];
#pragma unroll
    for (int j = 0; j < 32; ++j) o[j] *= dv;
    __half* gp = g + (size_t)n * 32;
    store_half8(gp,      o);
    store_half8(gp + 8,  o + 8);
    store_half8(gp + 16, o + 16);
    store_half8(gp + 24, o + 24);
}

// ---- phase A: Spart[n] = g[n] + sum_{src<HALFN} g[src]; hot set = g[0..HALFN) ----
__global__ __launch_bounds__(256) void k_gatherA(
        const int* __restrict__ rowptr, const int* __restrict__ rowmid,
        const int* __restrict__ csr_src, const __half* __restrict__ gin,
        float* __restrict__ Spart) {
    int tid = blockIdx.x * 256 + threadIdx.x;
    int n = tid >> 2;
    if (n >= N_NODES) return;
    int sub = tid & 3;
    float acc[8];
    float4 self = *(const float4*)(gin + (size_t)n * 32 + sub * 8);
    {
        __half2* hp = (__half2*)&self;
#pragma unroll
        for (int i = 0; i < 4; ++i) {
            float2 f = __half22float2(hp[i]);
            acc[2 * i] = f.x;
            acc[2 * i + 1] = f.y;
        }
    }
    int beg = rowptr[n], end = rowmid[n];
    int k = beg;
    for (; k + 3 < end; k += 4) {
        int s0 = nt_ld(csr_src + k),     s1 = nt_ld(csr_src + k + 1);
        int s2 = nt_ld(csr_src + k + 2), s3 = nt_ld(csr_src + k + 3);
        float4 r0 = *(const float4*)(gin + (size_t)s0 * 32 + sub * 8);
        float4 r1 = *(const float4*)(gin + (size_t)s1 * 32 + sub * 8);
        float4 r2 = *(const float4*)(gin + (size_t)s2 * 32 + sub * 8);
        float4 r3 = *(const float4*)(gin + (size_t)s3 * 32 + sub * 8);
        acc_half8(acc, r0); acc_half8(acc, r1);
        acc_half8(acc, r2); acc_half8(acc, r3);
    }
    for (; k < end; ++k) {
        int s = nt_ld(csr_src + k);
        float4 r = *(const float4*)(gin + (size_t)s * 32 + sub * 8);
        acc_half8(acc, r);
    }
    float* sp = Spart + (size_t)n * 32 + sub * 8;
    nt_st4(sp, make_float4(acc[0], acc[1], acc[2], acc[3]));
    nt_st4(sp + 4, make_float4(acc[4], acc[5], acc[6], acc[7]));
}

// ---- phase B + mid MLP ----
__global__ __launch_bounds__(256) void k_gatherB_mid(
        const int* __restrict__ rowptr, const int* __restrict__ rowmid,
        const int* __restrict__ csr_src, const __half* __restrict__ gin,
        const float* __restrict__ Spart, const float* __restrict__ dinv,
        const float* __restrict__ b, const float* __restrict__ W,
        __half* __restrict__ gout) {
    __shared__ float sS[64 * 33];
    __shared__ float sW[1024];
    __shared__ float sb[32];
    for (int i = threadIdx.x; i < 1024; i += 256) sW[i] = W[i];
    if (threadIdx.x < 32) sb[threadIdx.x] = b[threadIdx.x];

    int nl = threadIdx.x >> 2;
    int sub = threadIdx.x & 3;
    int n = blockIdx.x * 64 + nl;
    float acc[8];
    if (n < N_NODES) {
        const float* sp = Spart + (size_t)n * 32 + sub * 8;
        float4 p0 = nt_ld4(sp);
        float4 p1 = nt_ld4(sp + 4);
        acc[0] = p0.x; acc[1] = p0.y; acc[2] = p0.z; acc[3] = p0.w;
        acc[4] = p1.x; acc[5] = p1.y; acc[6] = p1.z; acc[7] = p1.w;
        int beg = rowmid[n], end = rowptr[n + 1];
        int k = beg;
        for (; k + 3 < end; k += 4) {
            int s0 = nt_ld(csr_src + k),     s1 = nt_ld(csr_src + k + 1);
            int s2 = nt_ld(csr_src + k + 2), s3 = nt_ld(csr_src + k + 3);
            float4 r0 = *(const float4*)(gin + (size_t)s0 * 32 + sub * 8);
            float4 r1 = *(const float4*)(gin + (size_t)s1 * 32 + sub * 8);
            float4 r2 = *(const float4*)(gin + (size_t)s2 * 32 + sub * 8);
            float4 r3 = *(const float4*)(gin + (size_t)s3 * 32 + sub * 8);
            acc_half8(acc, r0); acc_half8(acc, r1);
            acc_half8(acc, r2); acc_half8(acc, r3);
        }
        for (; k < end; ++k) {
            int s = nt_ld(csr_src + k);
            float4 r = *(const float4*)(gin + (size_t)s * 32 + sub * 8);
            acc_half8(acc, r);
        }
#pragma unroll
        for (int i = 0; i < 8; ++i) sS[nl * 33 + sub * 8 + i] = acc[i];
    }
    __syncthreads();

    if (n >= N_NODES) return;
    float dv = dinv[n];
    float t[32];
#pragma unroll
    for (int kk = 0; kk < 32; ++kk)
        t[kk] = fmaxf(fmaf(dv, sS[nl * 33 + kk], sb[kk]), 0.0f);
    float o[8];
#pragma unroll
    for (int j = 0; j < 8; ++j) o[j] = 0.f;
#pragma unroll
    for (int kk = 0; kk < 32; ++kk) {
        float a = t[kk];
#pragma unroll
        for (int j = 0; j < 8; ++j)
            o[j] = fmaf(a, sW[kk * 32 + sub * 8 + j], o[j]);
    }
#pragma unroll
    for (int j = 0; j < 8; ++j) o[j] *= dv;
    store_half8(gout + (size_t)n * 32 + sub * 8, o);
}

// ---- phase B + final layer ----
__global__ __launch_bounds__(256) void k_gatherB_out(
        const int* __restrict__ rowptr, const int* __restrict__ rowmid,
        const int* __restrict__ csr_src, const __half* __restrict__ gin,
        const float* __restrict__ Spart, const float* __restrict__ dinv,
        const float* __restrict__ bc3, const float* __restrict__ Wfc2,
        const float* __restrict__ bfc2, float* __restrict__ out) {
    __shared__ float sS[64 * 33];
    __shared__ float sW[96];
    __shared__ float sb[32];
    __shared__ float sb2[3];
    if (threadIdx.x < 96) sW[threadIdx.x] = Wfc2[threadIdx.x];
    if (threadIdx.x < 32) sb[threadIdx.x] = bc3[threadIdx.x];
    if (threadIdx.x < 3)  sb2[threadIdx.x] = bfc2[threadIdx.x];

    int nl = threadIdx.x >> 2;
    int sub = threadIdx.x & 3;
    int n = blockIdx.x * 64 + nl;
    float acc[8];
    if (n < N_NODES) {
        const float* sp = Spart + (size_t)n * 32 + sub * 8;
        float4 p0 = nt_ld4(sp);
        float4 p1 = nt_ld4(sp + 4);
        acc[0] = p0.x; acc[1] = p0.y; acc[2] = p0.z; acc[3] = p0.w;
        acc[4] = p1.x; acc[5] = p1.y; acc[6] = p1.z; acc[7] = p1.w;
        int beg = rowmid[n], end = rowptr[n + 1];
        int k = beg;
        for (; k + 3 < end; k += 4) {
            int s0 = nt_ld(csr_src + k),     s1 = nt_ld(csr_src + k + 1);
            int s2 = nt_ld(csr_src + k + 2), s3 = nt_ld(csr_src + k + 3);
            float4 r0 = *(const float4*)(gin + (size_t)s0 * 32 + sub * 8);
            float4 r1 = *(const float4*)(gin + (size_t)s1 * 32 + sub * 8);
            float4 r2 = *(const float4*)(gin + (size_t)s2 * 32 + sub * 8);
            float4 r3 = *(const float4*)(gin + (size_t)s3 * 32 + sub * 8);
            acc_half8(acc, r0); acc_half8(acc, r1);
            acc_half8(acc, r2); acc_half8(acc, r3);
        }
        for (; k < end; ++k) {
            int s = nt_ld(csr_src + k);
            float4 r = *(const float4*)(gin + (size_t)s * 32 + sub * 8);
            acc_half8(acc, r);
        }
#pragma unroll
        for (int i = 0; i < 8; ++i) sS[nl * 33 + sub * 8 + i] = acc[i];
    }
    __syncthreads();

    if (n >= N_NODES || sub != 0) return;
    float dv = dinv[n];
    float t[32];
#pragma unroll
    for (int kk = 0; kk < 32; ++kk)
        t[kk] = fmaxf(fmaf(dv, sS[nl * 33 + kk], sb[kk]), 0.0f);
    float o0 = sb2[0], o1 = sb2[1], o2 = sb2[2];
#pragma unroll
    for (int kk = 0; kk < 32; ++kk) {
        o0 = fmaf(t[kk], sW[kk * 3 + 0], o0);
        o1 = fmaf(t[kk], sW[kk * 3 + 1], o1);
        o2 = fmaf(t[kk], sW[kk * 3 + 2], o2);
    }
    out[(size_t)n * 3 + 0] = o0;
    out[(size_t)n * 3 + 1] = o1;
    out[(size_t)n * 3 + 2] = o2;
}

extern "C" void kernel_launch(void* const* d_in, const int* in_sizes, int n_in,
                              void* d_out, int out_size, void* d_ws, size_t ws_size,
                              hipStream_t stream) {
    const float* x    = (const float*)d_in[0];
    const int*   ei   = (const int*)d_in[1];
    const float* Wfc1 = (const float*)d_in[2];
    const float* bfc1 = (const float*)d_in[3];
    const float* Wc1  = (const float*)d_in[4];
    const float* bc1  = (const float*)d_in[5];
    const float* Wc2  = (const float*)d_in[6];
    const float* bc2  = (const float*)d_in[7];
    const float* Wc3  = (const float*)d_in[8];
    const float* bc3  = (const float*)d_in[9];
    const float* Wfc2 = (const float*)d_in[10];
    const float* bfc2 = (const float*)d_in[11];
    float* out = (float*)d_out;

    char* ws = (char*)d_ws;
    const size_t grow  = (size_t)N_NODES * 32 * sizeof(__half);   // 6.4 MB
    const size_t srow  = (size_t)N_NODES * 32 * sizeof(float);    // 12.8 MB
    size_t off = 0;
    __half* gA     = (__half*)(ws + off); off += grow;
    __half* gB     = (__half*)(ws + off); off += grow;
    float*  Spart  = (float*) (ws + off); off += srow;
    int*   binned  = (int*)  (ws + off); off += (size_t)N_EDGES * sizeof(int);
    int*   csr_src = (int*)  (ws + off); off += (size_t)N_EDGES * sizeof(int);
    float* dinv    = (float*)(ws + off); off += (size_t)N_NODES * sizeof(float);
    int*   rowptr  = (int*)  (ws + off); off += (size_t)(N_NODES + 1) * sizeof(int);
    int*   rowmid  = (int*)  (ws + off); off += (size_t)N_NODES * sizeof(int);
    int*   blkbin  = (int*)  (ws + off); off += (size_t)NBUCK * NBLK * sizeof(int);
    int*   blkoff  = (int*)  (ws + off); off += (size_t)NBUCK * NBLK * sizeof(int);
    int*   bintot  = (int*)  (ws + off); off += (size_t)NBUCK * sizeof(int);
    int*   binoff  = (int*)  (ws + off); off += (size_t)(NBUCK + 1) * sizeof(int);

    const int nb_wave = (NBUCK + 3) / 4;              // 98
    const int nb_n = (N_NODES + 255) / 256;           // 391
    const int nb_a = (N_NODES * 4 + 255) / 256;       // 1563 (4 thr/node)

    k_bincount<<<NBLK, 256, 0, stream>>>(ei, blkbin);
    k_bintot<<<nb_wave, 256, 0, stream>>>(blkbin, bintot);
    k_binscan<<<1, 512, 0, stream>>>(bintot, binoff);
    k_blkoff<<<nb_wave, 256, 0, stream>>>(blkbin, binoff, blkoff);
    k_binfill<<<NBLK, 256, 0, stream>>>(ei, blkoff, binned);
    k_sortdeg<<<NBUCK, 512, 0, stream>>>(binned, binoff, csr_src, rowptr, rowmid, dinv);

    k_fc1_conv1<<<nb_n, 256, 0, stream>>>(x, Wfc1, bfc1, Wc1, dinv, gA);

    k_gatherA<<<nb_a, 256, 0, stream>>>(rowptr, rowmid, csr_src, gA, Spart);
    k_gatherB_mid<<<nb_a, 256, 0, stream>>>(rowptr, rowmid, csr_src, gA, Spart, dinv, bc1, Wc2, gB);

    k_gatherA<<<nb_a, 256, 0, stream>>>(rowptr, rowmid, csr_src, gB, Spart);
    k_gatherB_mid<<<nb_a, 256, 0, stream>>>(rowptr, rowmid, csr_src, gB, Spart, dinv, bc2, Wc3, gA);

    k_gatherA<<<nb_a, 256, 0, stream>>>(rowptr, rowmid, csr_src, gA, Spart);
    k_gatherB_out<<<nb_a, 256, 0, stream>>>(rowptr, rowmid, csr_src, gA, Spart, dinv, bc3, Wfc2, bfc2, out);
}

// Round 9
// 281.033 us; speedup vs baseline: 1.1232x; 1.1232x over previous
//
#include <hip/hip_runtime.h>
#include <hip/hip_fp16.h>

// GCN: 100K nodes, 2.5M edges, dims 4 -> 32 -> (32x32 conv x3) -> 3.
// Round 9: revert R8's nt hints (regression: killed csr_src wave-reuse and
// forced Spart to HBM) and R6's phase split (neutral). Back to R5 structure
// (fp16 g, fused gather+MLP, atomic-free build) with:
//  - build parallelism x4: NBLK 256 -> 1024 (bincount/binfill were 1 block/CU)
//  - gather edge-loop unroll x4 -> x8 (gathers are latency-bound: VALUBusy 9%)
// g fp16 (64B rows, 16B/lane x 4 lanes/node); accumulate fp32.

constexpr int N_NODES = 100000;
constexpr int N_EDGES = 2500000;
constexpr int BUCKET  = 256;
constexpr int NBUCK   = (N_NODES + BUCKET - 1) / BUCKET;   // 391
constexpr int NBLK    = 1024;                              // build blocks (4/CU)
constexpr int CHUNK   = (N_EDGES + NBLK - 1) / NBLK;       // 2442
constexpr int PERLANE = NBLK / 64;                         // 16

// ================= build =================
__global__ __launch_bounds__(256) void k_bincount(const int* __restrict__ ei,
                                                  int* __restrict__ blkbin) {
    __shared__ int hist[NBUCK];
    for (int i = threadIdx.x; i < NBUCK; i += 256) hist[i] = 0;
    __syncthreads();
    int beg = blockIdx.x * CHUNK;
    int end = min(beg + CHUNK, N_EDGES);
    for (int e = beg + threadIdx.x; e < end; e += 256) {
        int d = ei[N_EDGES + e];
        atomicAdd(&hist[d >> 8], 1);
    }
    __syncthreads();
    for (int i = threadIdx.x; i < NBUCK; i += 256)
        blkbin[i * NBLK + blockIdx.x] = hist[i];      // bin-major
}

__global__ __launch_bounds__(256) void k_bintot(const int* __restrict__ blkbin,
                                                int* __restrict__ bintot) {
    int w = threadIdx.x >> 6, lane = threadIdx.x & 63;
    int bin = blockIdx.x * 4 + w;
    if (bin >= NBUCK) return;
    int s = 0;
    for (int k = lane; k < NBLK; k += 64) s += blkbin[bin * NBLK + k];
#pragma unroll
    for (int o = 32; o > 0; o >>= 1) s += __shfl_down(s, o);
    if (lane == 0) bintot[bin] = s;
}

__global__ __launch_bounds__(512) void k_binscan(const int* __restrict__ bintot,
                                                 int* __restrict__ binoff) {
    __shared__ int sc[512];
    int tid = threadIdx.x;
    int v = (tid < NBUCK) ? bintot[tid] : 0;
    sc[tid] = v;
    __syncthreads();
#pragma unroll
    for (int o = 1; o < 512; o <<= 1) {
        int t = (tid >= o) ? sc[tid - o] : 0;
        __syncthreads();
        sc[tid] += t;
        __syncthreads();
    }
    if (tid < NBUCK) binoff[tid] = sc[tid] - v;
    if (tid == NBUCK - 1) binoff[NBUCK] = sc[tid];
}

__global__ __launch_bounds__(256) void k_blkoff(const int* __restrict__ blkbin,
                                                const int* __restrict__ binoff,
                                                int* __restrict__ blkoff) {
    int w = threadIdx.x >> 6, lane = threadIdx.x & 63;
    int bin = blockIdx.x * 4 + w;
    if (bin >= NBUCK) return;
    int v[PERLANE];
#pragma unroll
    for (int i = 0; i < PERLANE; ++i) v[i] = blkbin[bin * NBLK + lane * PERLANE + i];
    int mysum = 0;
#pragma unroll
    for (int i = 0; i < PERLANE; ++i) mysum += v[i];
    int pre = mysum;
#pragma unroll
    for (int o = 1; o < 64; o <<= 1) {
        int t = __shfl_up(pre, o);
        if (lane >= o) pre += t;
    }
    pre -= mysum;                                      // exclusive across lanes
    int run = binoff[bin] + pre;
#pragma unroll
    for (int i = 0; i < PERLANE; ++i) {
        blkoff[bin * NBLK + lane * PERLANE + i] = run;
        run += v[i];
    }
}

__global__ __launch_bounds__(256) void k_binfill(const int* __restrict__ ei,
                                                 const int* __restrict__ blkoff,
                                                 int* __restrict__ binned) {
    __shared__ int cur[NBUCK];
    for (int i = threadIdx.x; i < NBUCK; i += 256)
        cur[i] = blkoff[i * NBLK + blockIdx.x];
    __syncthreads();
    int beg = blockIdx.x * CHUNK;
    int end = min(beg + CHUNK, N_EDGES);
    for (int e = beg + threadIdx.x; e < end; e += 256) {
        int s = ei[e];
        int d = ei[N_EDGES + e];
        int pos = atomicAdd(&cur[d >> 8], 1);
        binned[pos] = (s << 8) | (d & 255);            // src<17b><<8 | dst_local<8b>
    }
}

// ---- within-bucket counting sort by dst_local -> per-node CSR + dinv ----
__global__ __launch_bounds__(256) void k_sortdeg(const int* __restrict__ binned,
                                                 const int* __restrict__ binoff,
                                                 int* __restrict__ csr_src,
                                                 int* __restrict__ rowptr,
                                                 float* __restrict__ dinv) {
    __shared__ int cnt[BUCKET];
    __shared__ int sc[BUCKET];
    __shared__ int cur[BUCKET];
    int tid = threadIdx.x;
    int b = blockIdx.x;
    int beg = binoff[b], end = binoff[b + 1];

    cnt[tid] = 0;
    __syncthreads();
    for (int k = beg + tid; k < end; k += 256)
        atomicAdd(&cnt[binned[k] & 255], 1);
    __syncthreads();

    int v = cnt[tid];
    sc[tid] = v;
    __syncthreads();
#pragma unroll
    for (int o = 1; o < 256; o <<= 1) {
        int t = (tid >= o) ? sc[tid - o] : 0;
        __syncthreads();
        sc[tid] += t;
        __syncthreads();
    }
    int excl = sc[tid] - v;
    cur[tid] = excl;
    int n = b * BUCKET + tid;
    if (n < N_NODES) {
        rowptr[n] = beg + excl;
        dinv[n] = rsqrtf((float)(v + 1));   // +1 self-loop
        if (n == N_NODES - 1) rowptr[N_NODES] = end;
    }
    __syncthreads();

    for (int k = beg + tid; k < end; k += 256) {
        int p = binned[k];
        int pos = atomicAdd(&cur[p & 255], 1);
        csr_src[beg + pos] = p >> 8;
    }
}

// ================= dense helpers =================
__device__ inline void store_half8(__half* p, const float* v) {
    __half2 h[4];
#pragma unroll
    for (int i = 0; i < 4; ++i)
        h[i] = __floats2half2_rn(v[2 * i], v[2 * i + 1]);
    *(float4*)p = *(float4*)h;
}

__device__ inline void acc_half8(float* acc, float4 raw) {
    __half2* hp = (__half2*)&raw;
#pragma unroll
    for (int i = 0; i < 4; ++i) {
        float2 f = __half22float2(hp[i]);
        acc[2 * i]     += f.x;
        acc[2 * i + 1] += f.y;
    }
}

// t = relu(x@Wfc1 + bfc1); g = half( dinv * (t@Wc1) )
__global__ __launch_bounds__(256) void k_fc1_conv1(
        const float* __restrict__ x,
        const float* __restrict__ Wfc1, const float* __restrict__ bfc1,
        const float* __restrict__ Wc1, const float* __restrict__ dinv,
        __half* __restrict__ g) {
    __shared__ float  sWf[128];
    __shared__ float  sbf[32];
    __shared__ float4 sW[256];
    if (threadIdx.x < 128) sWf[threadIdx.x] = Wfc1[threadIdx.x];
    if (threadIdx.x < 32)  sbf[threadIdx.x] = bfc1[threadIdx.x];
    sW[threadIdx.x] = ((const float4*)Wc1)[threadIdx.x];
    __syncthreads();

    int n = blockIdx.x * 256 + threadIdx.x;
    if (n >= N_NODES) return;

    float4 xin = *(const float4*)(x + (size_t)n * 4);
    float t[32];
#pragma unroll
    for (int j = 0; j < 32; ++j) {
        float a = fmaf(xin.x, sWf[j], sbf[j]);
        a = fmaf(xin.y, sWf[32 + j], a);
        a = fmaf(xin.z, sWf[64 + j], a);
        a = fmaf(xin.w, sWf[96 + j], a);
        t[j] = fmaxf(a, 0.0f);
    }
    float o[32];
#pragma unroll
    for (int j = 0; j < 32; ++j) o[j] = 0.f;
#pragma unroll
    for (int k = 0; k < 32; ++k) {
        float a = t[k];
#pragma unroll
        for (int q = 0; q < 8; ++q) {
            float4 w = sW[k * 8 + q];
            o[q * 4 + 0] = fmaf(a, w.x, o[q * 4 + 0]);
            o[q * 4 + 1] = fmaf(a, w.y, o[q * 4 + 1]);
            o[q * 4 + 2] = fmaf(a, w.z, o[q * 4 + 2]);
            o[q * 4 + 3] = fmaf(a, w.w, o[q * 4 + 3]);
        }
    }
    float dv = dinv[n];
#pragma unroll
    for (int j = 0; j < 32; ++j) o[j] *= dv;
    __half* gp = g + (size_t)n * 32;
    store_half8(gp,      o);
    store_half8(gp + 8,  o + 8);
    store_half8(gp + 16, o + 16);
    store_half8(gp + 24, o + 24);
}

// ---- fused gather + mid MLP: 4 threads/node, 64 nodes/block, unroll x8 ----
__global__ __launch_bounds__(256) void k_gather_mid(
        const int* __restrict__ rowptr, const int* __restrict__ csr_src,
        const __half* __restrict__ gin, const float* __restrict__ dinv,
        const float* __restrict__ b, const float* __restrict__ W,
        __half* __restrict__ gout) {
    __shared__ float sS[64 * 33];
    __shared__ float sW[1024];
    __shared__ float sb[32];
    for (int i = threadIdx.x; i < 1024; i += 256) sW[i] = W[i];
    if (threadIdx.x < 32) sb[threadIdx.x] = b[threadIdx.x];

    int nl = threadIdx.x >> 2;
    int sub = threadIdx.x & 3;
    int n = blockIdx.x * 64 + nl;
    float acc[8];
    if (n < N_NODES) {
        float4 self = *(const float4*)(gin + (size_t)n * 32 + sub * 8);
        {
            __half2* hp = (__half2*)&self;
#pragma unroll
            for (int i = 0; i < 4; ++i) {
                float2 f = __half22float2(hp[i]);
                acc[2 * i] = f.x;
                acc[2 * i + 1] = f.y;
            }
        }
        int beg = rowptr[n], end = rowptr[n + 1];
        int k = beg;
        for (; k + 7 < end; k += 8) {
            int s[8];
#pragma unroll
            for (int i = 0; i < 8; ++i) s[i] = csr_src[k + i];
            float4 r[8];
#pragma unroll
            for (int i = 0; i < 8; ++i)
                r[i] = *(const float4*)(gin + (size_t)s[i] * 32 + sub * 8);
#pragma unroll
            for (int i = 0; i < 8; ++i) acc_half8(acc, r[i]);
        }
        for (; k < end; ++k) {
            int s = csr_src[k];
            float4 r = *(const float4*)(gin + (size_t)s * 32 + sub * 8);
            acc_half8(acc, r);
        }
#pragma unroll
        for (int i = 0; i < 8; ++i) sS[nl * 33 + sub * 8 + i] = acc[i];
    }
    __syncthreads();

    if (n >= N_NODES) return;
    float dv = dinv[n];
    float t[32];
#pragma unroll
    for (int kk = 0; kk < 32; ++kk)
        t[kk] = fmaxf(fmaf(dv, sS[nl * 33 + kk], sb[kk]), 0.0f);
    float o[8];
#pragma unroll
    for (int j = 0; j < 8; ++j) o[j] = 0.f;
#pragma unroll
    for (int kk = 0; kk < 32; ++kk) {
        float a = t[kk];
#pragma unroll
        for (int j = 0; j < 8; ++j)
            o[j] = fmaf(a, sW[kk * 32 + sub * 8 + j], o[j]);
    }
#pragma unroll
    for (int j = 0; j < 8; ++j) o[j] *= dv;
    store_half8(gout + (size_t)n * 32 + sub * 8, o);
}

// ---- fused gather + final layer ----
__global__ __launch_bounds__(256) void k_gather_out(
        const int* __restrict__ rowptr, const int* __restrict__ csr_src,
        const __half* __restrict__ gin, const float* __restrict__ dinv,
        const float* __restrict__ bc3, const float* __restrict__ Wfc2,
        const float* __restrict__ bfc2, float* __restrict__ out) {
    __shared__ float sS[64 * 33];
    __shared__ float sW[96];
    __shared__ float sb[32];
    __shared__ float sb2[3];
    if (threadIdx.x < 96) sW[threadIdx.x] = Wfc2[threadIdx.x];
    if (threadIdx.x < 32) sb[threadIdx.x] = bc3[threadIdx.x];
    if (threadIdx.x < 3)  sb2[threadIdx.x] = bfc2[threadIdx.x];

    int nl = threadIdx.x >> 2;
    int sub = threadIdx.x & 3;
    int n = blockIdx.x * 64 + nl;
    float acc[8];
    if (n < N_NODES) {
        float4 self = *(const float4*)(gin + (size_t)n * 32 + sub * 8);
        {
            __half2* hp = (__half2*)&self;
#pragma unroll
            for (int i = 0; i < 4; ++i) {
                float2 f = __half22float2(hp[i]);
                acc[2 * i] = f.x;
                acc[2 * i + 1] = f.y;
            }
        }
        int beg = rowptr[n], end = rowptr[n + 1];
        int k = beg;
        for (; k + 7 < end; k += 8) {
            int s[8];
#pragma unroll
            for (int i = 0; i < 8; ++i) s[i] = csr_src[k + i];
            float4 r[8];
#pragma unroll
            for (int i = 0; i < 8; ++i)
                r[i] = *(const float4*)(gin + (size_t)s[i] * 32 + sub * 8);
#pragma unroll
            for (int i = 0; i < 8; ++i) acc_half8(acc, r[i]);
        }
        for (; k < end; ++k) {
            int s = csr_src[k];
            float4 r = *(const float4*)(gin + (size_t)s * 32 + sub * 8);
            acc_half8(acc, r);
        }
#pragma unroll
        for (int i = 0; i < 8; ++i) sS[nl * 33 + sub * 8 + i] = acc[i];
    }
    __syncthreads();

    if (n >= N_NODES || sub != 0) return;
    float dv = dinv[n];
    float t[32];
#pragma unroll
    for (int kk = 0; kk < 32; ++kk)
        t[kk] = fmaxf(fmaf(dv, sS[nl * 33 + kk], sb[kk]), 0.0f);
    float o0 = sb2[0], o1 = sb2[1], o2 = sb2[2];
#pragma unroll
    for (int kk = 0; kk < 32; ++kk) {
        o0 = fmaf(t[kk], sW[kk * 3 + 0], o0);
        o1 = fmaf(t[kk], sW[kk * 3 + 1], o1);
        o2 = fmaf(t[kk], sW[kk * 3 + 2], o2);
    }
    out[(size_t)n * 3 + 0] = o0;
    out[(size_t)n * 3 + 1] = o1;
    out[(size_t)n * 3 + 2] = o2;
}

extern "C" void kernel_launch(void* const* d_in, const int* in_sizes, int n_in,
                              void* d_out, int out_size, void* d_ws, size_t ws_size,
                              hipStream_t stream) {
    const float* x    = (const float*)d_in[0];
    const int*   ei   = (const int*)d_in[1];
    const float* Wfc1 = (const float*)d_in[2];
    const float* bfc1 = (const float*)d_in[3];
    const float* Wc1  = (const float*)d_in[4];
    const float* bc1  = (const float*)d_in[5];
    const float* Wc2  = (const float*)d_in[6];
    const float* bc2  = (const float*)d_in[7];
    const float* Wc3  = (const float*)d_in[8];
    const float* bc3  = (const float*)d_in[9];
    const float* Wfc2 = (const float*)d_in[10];
    const float* bfc2 = (const float*)d_in[11];
    float* out = (float*)d_out;

    char* ws = (char*)d_ws;
    const size_t grow = (size_t)N_NODES * 32 * sizeof(__half);   // 6.4 MB
    size_t off = 0;
    __half* gA     = (__half*)(ws + off); off += grow;
    __half* gB     = (__half*)(ws + off); off += grow;
    int*   binned  = (int*)  (ws + off); off += (size_t)N_EDGES * sizeof(int);
    int*   csr_src = (int*)  (ws + off); off += (size_t)N_EDGES * sizeof(int);
    float* dinv    = (float*)(ws + off); off += (size_t)N_NODES * sizeof(float);
    int*   rowptr  = (int*)  (ws + off); off += (size_t)(N_NODES + 1) * sizeof(int);
    int*   blkbin  = (int*)  (ws + off); off += (size_t)NBUCK * NBLK * sizeof(int);
    int*   blkoff  = (int*)  (ws + off); off += (size_t)NBUCK * NBLK * sizeof(int);
    int*   bintot  = (int*)  (ws + off); off += (size_t)NBUCK * sizeof(int);
    int*   binoff  = (int*)  (ws + off); off += (size_t)(NBUCK + 1) * sizeof(int);

    const int nb_wave = (NBUCK + 3) / 4;              // 98
    const int nb_n = (N_NODES + 255) / 256;           // 391
    const int nb_f = (N_NODES * 4 + 255) / 256;       // 1563 (4 thr/node)

    k_bincount<<<NBLK, 256, 0, stream>>>(ei, blkbin);
    k_bintot<<<nb_wave, 256, 0, stream>>>(blkbin, bintot);
    k_binscan<<<1, 512, 0, stream>>>(bintot, binoff);
    k_blkoff<<<nb_wave, 256, 0, stream>>>(blkbin, binoff, blkoff);
    k_binfill<<<NBLK, 256, 0, stream>>>(ei, blkoff, binned);
    k_sortdeg<<<NBUCK, 256, 0, stream>>>(binned, binoff, csr_src, rowptr, dinv);

    k_fc1_conv1<<<nb_n, 256, 0, stream>>>(x, Wfc1, bfc1, Wc1, dinv, gA);
    k_gather_mid<<<nb_f, 256, 0, stream>>>(rowptr, csr_src, gA, dinv, bc1, Wc2, gB);
    k_gather_mid<<<nb_f, 256, 0, stream>>>(rowptr, csr_src, gB, dinv, bc2, Wc3, gA);
    k_gather_out<<<nb_f, 256, 0, stream>>>(rowptr, csr_src, gA, dinv, bc3, Wfc2, bfc2, out);
}

// Round 10
// 254.923 us; speedup vs baseline: 1.2383x; 1.1024x over previous
//
#include <hip/hip_runtime.h>
#include <hip/hip_fp16.h>

// GCN: 100K nodes, 2.5M edges, dims 4 -> 32 -> (32x32 conv x3) -> 3.
// Round 10: SOFT-PHASED gather. R4-R9 FETCH analysis says gather cost is
// per-XCD L2 misses on the random g reads (g=6.4MB > 4MB L2/XCD). R6's
// dispatch-level phase split was right but paid a 25.6MB/layer Spart round
// trip. Here both src-half phases run inside ONE kernel with acc in REGISTERS:
// all blocks are co-resident (6/CU) and do near-identical work, so they
// traverse phase A (src<50K, hot 3.2MB = L2-resident) approximately together,
// then phase B. Phase order never affects correctness, only locality.
// Also: unroll back to x4 (x8 regressed in R9). Build from R9 + 512-key
// sortdeg (R6) for rowmid.

constexpr int N_NODES = 100000;
constexpr int N_EDGES = 2500000;
constexpr int HALFN   = 50000;
constexpr int BUCKET  = 256;
constexpr int NBUCK   = (N_NODES + BUCKET - 1) / BUCKET;   // 391
constexpr int NBLK    = 1024;                              // build blocks
constexpr int CHUNK   = (N_EDGES + NBLK - 1) / NBLK;       // 2442
constexpr int PERLANE = NBLK / 64;                         // 16

// ================= build =================
__global__ __launch_bounds__(256) void k_bincount(const int* __restrict__ ei,
                                                  int* __restrict__ blkbin) {
    __shared__ int hist[NBUCK];
    for (int i = threadIdx.x; i < NBUCK; i += 256) hist[i] = 0;
    __syncthreads();
    int beg = blockIdx.x * CHUNK;
    int end = min(beg + CHUNK, N_EDGES);
    for (int e = beg + threadIdx.x; e < end; e += 256) {
        int d = ei[N_EDGES + e];
        atomicAdd(&hist[d >> 8], 1);
    }
    __syncthreads();
    for (int i = threadIdx.x; i < NBUCK; i += 256)
        blkbin[i * NBLK + blockIdx.x] = hist[i];      // bin-major
}

__global__ __launch_bounds__(256) void k_bintot(const int* __restrict__ blkbin,
                                                int* __restrict__ bintot) {
    int w = threadIdx.x >> 6, lane = threadIdx.x & 63;
    int bin = blockIdx.x * 4 + w;
    if (bin >= NBUCK) return;
    int s = 0;
    for (int k = lane; k < NBLK; k += 64) s += blkbin[bin * NBLK + k];
#pragma unroll
    for (int o = 32; o > 0; o >>= 1) s += __shfl_down(s, o);
    if (lane == 0) bintot[bin] = s;
}

__global__ __launch_bounds__(512) void k_binscan(const int* __restrict__ bintot,
                                                 int* __restrict__ binoff) {
    __shared__ int sc[512];
    int tid = threadIdx.x;
    int v = (tid < NBUCK) ? bintot[tid] : 0;
    sc[tid] = v;
    __syncthreads();
#pragma unroll
    for (int o = 1; o < 512; o <<= 1) {
        int t = (tid >= o) ? sc[tid - o] : 0;
        __syncthreads();
        sc[tid] += t;
        __syncthreads();
    }
    if (tid < NBUCK) binoff[tid] = sc[tid] - v;
    if (tid == NBUCK - 1) binoff[NBUCK] = sc[tid];
}

__global__ __launch_bounds__(256) void k_blkoff(const int* __restrict__ blkbin,
                                                const int* __restrict__ binoff,
                                                int* __restrict__ blkoff) {
    int w = threadIdx.x >> 6, lane = threadIdx.x & 63;
    int bin = blockIdx.x * 4 + w;
    if (bin >= NBUCK) return;
    int v[PERLANE];
#pragma unroll
    for (int i = 0; i < PERLANE; ++i) v[i] = blkbin[bin * NBLK + lane * PERLANE + i];
    int mysum = 0;
#pragma unroll
    for (int i = 0; i < PERLANE; ++i) mysum += v[i];
    int pre = mysum;
#pragma unroll
    for (int o = 1; o < 64; o <<= 1) {
        int t = __shfl_up(pre, o);
        if (lane >= o) pre += t;
    }
    pre -= mysum;
    int run = binoff[bin] + pre;
#pragma unroll
    for (int i = 0; i < PERLANE; ++i) {
        blkoff[bin * NBLK + lane * PERLANE + i] = run;
        run += v[i];
    }
}

__global__ __launch_bounds__(256) void k_binfill(const int* __restrict__ ei,
                                                 const int* __restrict__ blkoff,
                                                 int* __restrict__ binned) {
    __shared__ int cur[NBUCK];
    for (int i = threadIdx.x; i < NBUCK; i += 256)
        cur[i] = blkoff[i * NBLK + blockIdx.x];
    __syncthreads();
    int beg = blockIdx.x * CHUNK;
    int end = min(beg + CHUNK, N_EDGES);
    for (int e = beg + threadIdx.x; e < end; e += 256) {
        int s = ei[e];
        int d = ei[N_EDGES + e];
        int pos = atomicAdd(&cur[d >> 8], 1);
        binned[pos] = (s << 8) | (d & 255);            // src<17b><<8 | dst_local<8b>
    }
}

// ---- within-bucket counting sort, key = dst_local*2 + (src>=HALFN) ----
__global__ __launch_bounds__(512) void k_sortdeg(const int* __restrict__ binned,
                                                 const int* __restrict__ binoff,
                                                 int* __restrict__ csr_src,
                                                 int* __restrict__ rowptr,
                                                 int* __restrict__ rowmid,
                                                 float* __restrict__ dinv) {
    __shared__ int cnt[512];
    __shared__ int sc[512];
    __shared__ int cur[512];
    int t = threadIdx.x;
    int b = blockIdx.x;
    int beg = binoff[b], end = binoff[b + 1];

    cnt[t] = 0;
    __syncthreads();
    for (int k = beg + t; k < end; k += 512) {
        int p = binned[k];
        int key = ((p & 255) << 1) | (((p >> 8) >= HALFN) ? 1 : 0);
        atomicAdd(&cnt[key], 1);
    }
    __syncthreads();

    int v = cnt[t];
    sc[t] = v;
    __syncthreads();
#pragma unroll
    for (int o = 1; o < 512; o <<= 1) {
        int tv = (t >= o) ? sc[t - o] : 0;
        __syncthreads();
        sc[t] += tv;
        __syncthreads();
    }
    int excl = sc[t] - v;
    cur[t] = excl;
    int dl = t >> 1;
    int n = b * 256 + dl;
    if (n < N_NODES) {
        if ((t & 1) == 0) {
            rowptr[n] = beg + excl;
            dinv[n] = rsqrtf((float)(cnt[t] + cnt[t + 1] + 1));  // +1 self-loop
        } else {
            rowmid[n] = beg + excl;
        }
    }
    if (b == NBUCK - 1 && t == 0) rowptr[N_NODES] = end;
    __syncthreads();

    for (int k = beg + t; k < end; k += 512) {
        int p = binned[k];
        int key = ((p & 255) << 1) | (((p >> 8) >= HALFN) ? 1 : 0);
        int pos = atomicAdd(&cur[key], 1);
        csr_src[beg + pos] = p >> 8;
    }
}

// ================= dense helpers =================
__device__ inline void store_half8(__half* p, const float* v) {
    __half2 h[4];
#pragma unroll
    for (int i = 0; i < 4; ++i)
        h[i] = __floats2half2_rn(v[2 * i], v[2 * i + 1]);
    *(float4*)p = *(float4*)h;
}

__device__ inline void acc_half8(float* acc, float4 raw) {
    __half2* hp = (__half2*)&raw;
#pragma unroll
    for (int i = 0; i < 4; ++i) {
        float2 f = __half22float2(hp[i]);
        acc[2 * i]     += f.x;
        acc[2 * i + 1] += f.y;
    }
}

// t = relu(x@Wfc1 + bfc1); g = half( dinv * (t@Wc1) )
__global__ __launch_bounds__(256) void k_fc1_conv1(
        const float* __restrict__ x,
        const float* __restrict__ Wfc1, const float* __restrict__ bfc1,
        const float* __restrict__ Wc1, const float* __restrict__ dinv,
        __half* __restrict__ g) {
    __shared__ float  sWf[128];
    __shared__ float  sbf[32];
    __shared__ float4 sW[256];
    if (threadIdx.x < 128) sWf[threadIdx.x] = Wfc1[threadIdx.x];
    if (threadIdx.x < 32)  sbf[threadIdx.x] = bfc1[threadIdx.x];
    sW[threadIdx.x] = ((const float4*)Wc1)[threadIdx.x];
    __syncthreads();

    int n = blockIdx.x * 256 + threadIdx.x;
    if (n >= N_NODES) return;

    float4 xin = *(const float4*)(x + (size_t)n * 4);
    float t[32];
#pragma unroll
    for (int j = 0; j < 32; ++j) {
        float a = fmaf(xin.x, sWf[j], sbf[j]);
        a = fmaf(xin.y, sWf[32 + j], a);
        a = fmaf(xin.z, sWf[64 + j], a);
        a = fmaf(xin.w, sWf[96 + j], a);
        t[j] = fmaxf(a, 0.0f);
    }
    float o[32];
#pragma unroll
    for (int j = 0; j < 32; ++j) o[j] = 0.f;
#pragma unroll
    for (int k = 0; k < 32; ++k) {
        float a = t[k];
#pragma unroll
        for (int q = 0; q < 8; ++q) {
            float4 w = sW[k * 8 + q];
            o[q * 4 + 0] = fmaf(a, w.x, o[q * 4 + 0]);
            o[q * 4 + 1] = fmaf(a, w.y, o[q * 4 + 1]);
            o[q * 4 + 2] = fmaf(a, w.z, o[q * 4 + 2]);
            o[q * 4 + 3] = fmaf(a, w.w, o[q * 4 + 3]);
        }
    }
    float dv = dinv[n];
#pragma unroll
    for (int j = 0; j < 32; ++j) o[j] *= dv;
    __half* gp = g + (size_t)n * 32;
    store_half8(gp,      o);
    store_half8(gp + 8,  o + 8);
    store_half8(gp + 16, o + 16);
    store_half8(gp + 24, o + 24);
}

// ---- edge-segment accumulate, unroll x4 ----
__device__ inline void gather_seg(int beg, int end, const int* __restrict__ csr_src,
                                  const __half* __restrict__ gin, int sub, float* acc) {
    int k = beg;
    for (; k + 3 < end; k += 4) {
        int s0 = csr_src[k], s1 = csr_src[k + 1];
        int s2 = csr_src[k + 2], s3 = csr_src[k + 3];
        float4 r0 = *(const float4*)(gin + (size_t)s0 * 32 + sub * 8);
        float4 r1 = *(const float4*)(gin + (size_t)s1 * 32 + sub * 8);
        float4 r2 = *(const float4*)(gin + (size_t)s2 * 32 + sub * 8);
        float4 r3 = *(const float4*)(gin + (size_t)s3 * 32 + sub * 8);
        acc_half8(acc, r0); acc_half8(acc, r1);
        acc_half8(acc, r2); acc_half8(acc, r3);
    }
    for (; k < end; ++k) {
        int s = csr_src[k];
        float4 r = *(const float4*)(gin + (size_t)s * 32 + sub * 8);
        acc_half8(acc, r);
    }
}

// ---- soft-phased fused gather + mid MLP: 4 threads/node, 64 nodes/block ----
__global__ __launch_bounds__(256) void k_gather_mid(
        const int* __restrict__ rowptr, const int* __restrict__ rowmid,
        const int* __restrict__ csr_src, const __half* __restrict__ gin,
        const float* __restrict__ dinv,
        const float* __restrict__ b, const float* __restrict__ W,
        __half* __restrict__ gout) {
    __shared__ float sS[64 * 33];
    __shared__ float sW[1024];
    __shared__ float sb[32];
    for (int i = threadIdx.x; i < 1024; i += 256) sW[i] = W[i];
    if (threadIdx.x < 32) sb[threadIdx.x] = b[threadIdx.x];

    int nl = threadIdx.x >> 2;
    int sub = threadIdx.x & 3;
    int n = blockIdx.x * 64 + nl;
    float acc[8];
    if (n < N_NODES) {
        float4 self = *(const float4*)(gin + (size_t)n * 32 + sub * 8);
        {
            __half2* hp = (__half2*)&self;
#pragma unroll
            for (int i = 0; i < 4; ++i) {
                float2 f = __half22float2(hp[i]);
                acc[2 * i] = f.x;
                acc[2 * i + 1] = f.y;
            }
        }
        int beg = rowptr[n], mid = rowmid[n], end = rowptr[n + 1];
        gather_seg(beg, mid, csr_src, gin, sub, acc);   // phase A: src < 50K
        gather_seg(mid, end, csr_src, gin, sub, acc);   // phase B: src >= 50K
#pragma unroll
        for (int i = 0; i < 8; ++i) sS[nl * 33 + sub * 8 + i] = acc[i];
    }
    __syncthreads();

    if (n >= N_NODES) return;
    float dv = dinv[n];
    float t[32];
#pragma unroll
    for (int kk = 0; kk < 32; ++kk)
        t[kk] = fmaxf(fmaf(dv, sS[nl * 33 + kk], sb[kk]), 0.0f);
    float o[8];
#pragma unroll
    for (int j = 0; j < 8; ++j) o[j] = 0.f;
#pragma unroll
    for (int kk = 0; kk < 32; ++kk) {
        float a = t[kk];
#pragma unroll
        for (int j = 0; j < 8; ++j)
            o[j] = fmaf(a, sW[kk * 32 + sub * 8 + j], o[j]);
    }
#pragma unroll
    for (int j = 0; j < 8; ++j) o[j] *= dv;
    store_half8(gout + (size_t)n * 32 + sub * 8, o);
}

// ---- soft-phased fused gather + final layer ----
__global__ __launch_bounds__(256) void k_gather_out(
        const int* __restrict__ rowptr, const int* __restrict__ rowmid,
        const int* __restrict__ csr_src, const __half* __restrict__ gin,
        const float* __restrict__ dinv,
        const float* __restrict__ bc3, const float* __restrict__ Wfc2,
        const float* __restrict__ bfc2, float* __restrict__ out) {
    __shared__ float sS[64 * 33];
    __shared__ float sW[96];
    __shared__ float sb[32];
    __shared__ float sb2[3];
    if (threadIdx.x < 96) sW[threadIdx.x] = Wfc2[threadIdx.x];
    if (threadIdx.x < 32) sb[threadIdx.x] = bc3[threadIdx.x];
    if (threadIdx.x < 3)  sb2[threadIdx.x] = bfc2[threadIdx.x];

    int nl = threadIdx.x >> 2;
    int sub = threadIdx.x & 3;
    int n = blockIdx.x * 64 + nl;
    float acc[8];
    if (n < N_NODES) {
        float4 self = *(const float4*)(gin + (size_t)n * 32 + sub * 8);
        {
            __half2* hp = (__half2*)&self;
#pragma unroll
            for (int i = 0; i < 4; ++i) {
                float2 f = __half22float2(hp[i]);
                acc[2 * i] = f.x;
                acc[2 * i + 1] = f.y;
            }
        }
        int beg = rowptr[n], mid = rowmid[n], end = rowptr[n + 1];
        gather_seg(beg, mid, csr_src, gin, sub, acc);
        gather_seg(mid, end, csr_src, gin, sub, acc);
#pragma unroll
        for (int i = 0; i < 8; ++i) sS[nl * 33 + sub * 8 + i] = acc[i];
    }
    __syncthreads();

    if (n >= N_NODES || sub != 0) return;
    float dv = dinv[n];
    float t[32];
#pragma unroll
    for (int kk = 0; kk < 32; ++kk)
        t[kk] = fmaxf(fmaf(dv, sS[nl * 33 + kk], sb[kk]), 0.0f);
    float o0 = sb2[0], o1 = sb2[1], o2 = sb2[2];
#pragma unroll
    for (int kk = 0; kk < 32; ++kk) {
        o0 = fmaf(t[kk], sW[kk * 3 + 0], o0);
        o1 = fmaf(t[kk], sW[kk * 3 + 1], o1);
        o2 = fmaf(t[kk], sW[kk * 3 + 2], o2);
    }
    out[(size_t)n * 3 + 0] = o0;
    out[(size_t)n * 3 + 1] = o1;
    out[(size_t)n * 3 + 2] = o2;
}

extern "C" void kernel_launch(void* const* d_in, const int* in_sizes, int n_in,
                              void* d_out, int out_size, void* d_ws, size_t ws_size,
                              hipStream_t stream) {
    const float* x    = (const float*)d_in[0];
    const int*   ei   = (const int*)d_in[1];
    const float* Wfc1 = (const float*)d_in[2];
    const float* bfc1 = (const float*)d_in[3];
    const float* Wc1  = (const float*)d_in[4];
    const float* bc1  = (const float*)d_in[5];
    const float* Wc2  = (const float*)d_in[6];
    const float* bc2  = (const float*)d_in[7];
    const float* Wc3  = (const float*)d_in[8];
    const float* bc3  = (const float*)d_in[9];
    const float* Wfc2 = (const float*)d_in[10];
    const float* bfc2 = (const float*)d_in[11];
    float* out = (float*)d_out;

    char* ws = (char*)d_ws;
    const size_t grow = (size_t)N_NODES * 32 * sizeof(__half);   // 6.4 MB
    size_t off = 0;
    __half* gA     = (__half*)(ws + off); off += grow;
    __half* gB     = (__half*)(ws + off); off += grow;
    int*   binned  = (int*)  (ws + off); off += (size_t)N_EDGES * sizeof(int);
    int*   csr_src = (int*)  (ws + off); off += (size_t)N_EDGES * sizeof(int);
    float* dinv    = (float*)(ws + off); off += (size_t)N_NODES * sizeof(float);
    int*   rowptr  = (int*)  (ws + off); off += (size_t)(N_NODES + 1) * sizeof(int);
    int*   rowmid  = (int*)  (ws + off); off += (size_t)N_NODES * sizeof(int);
    int*   blkbin  = (int*)  (ws + off); off += (size_t)NBUCK * NBLK * sizeof(int);
    int*   blkoff  = (int*)  (ws + off); off += (size_t)NBUCK * NBLK * sizeof(int);
    int*   bintot  = (int*)  (ws + off); off += (size_t)NBUCK * sizeof(int);
    int*   binoff  = (int*)  (ws + off); off += (size_t)(NBUCK + 1) * sizeof(int);

    const int nb_wave = (NBUCK + 3) / 4;              // 98
    const int nb_n = (N_NODES + 255) / 256;           // 391
    const int nb_f = (N_NODES * 4 + 255) / 256;       // 1563 (4 thr/node)

    k_bincount<<<NBLK, 256, 0, stream>>>(ei, blkbin);
    k_bintot<<<nb_wave, 256, 0, stream>>>(blkbin, bintot);
    k_binscan<<<1, 512, 0, stream>>>(bintot, binoff);
    k_blkoff<<<nb_wave, 256, 0, stream>>>(blkbin, binoff, blkoff);
    k_binfill<<<NBLK, 256, 0, stream>>>(ei, blkoff, binned);
    k_sortdeg<<<NBUCK, 512, 0, stream>>>(binned, binoff, csr_src, rowptr, rowmid, dinv);

    k_fc1_conv1<<<nb_n, 256, 0, stream>>>(x, Wfc1, bfc1, Wc1, dinv, gA);
    k_gather_mid<<<nb_f, 256, 0, stream>>>(rowptr, rowmid, csr_src, gA, dinv, bc1, Wc2, gB);
    k_gather_mid<<<nb_f, 256, 0, stream>>>(rowptr, rowmid, csr_src, gB, dinv, bc2, Wc3, gA);
    k_gather_out<<<nb_f, 256, 0, stream>>>(rowptr, rowmid, csr_src, gA, dinv, bc3, Wfc2, bfc2, out);
}

// Round 11
// 240.831 us; speedup vs baseline: 1.3107x; 1.0585x over previous
//
#include <hip/hip_runtime.h>
#include <hip/hip_fp16.h>

// GCN: 100K nodes, 2.5M edges, dims 4 -> 32 -> (32x32 conv x3) -> 3.
// Round 11: SCATTER-FREE BUILD. R10 showed k_binfill at 45us with 59MB
// WRITE_SIZE for 10MB logical: bin-major layout puts adjacent (bucket,block)
// runs (~25B each) on shared 64B lines written by different XCDs ->
// false-sharing RMW thrash. Fix: block-major binned layout. Each build block
// counting-sorts its own chunk in LDS and streams it out contiguously
// (amplification=1), also emitting its histogram (blkbin) + run starts
// (locoff). k_bincount and k_blkoff are eliminated. k_sortdeg assembles each
// bucket from 1024 short runs into a 32KB LDS stage (read-side amplification,
// L3-served) then does the 512-key (dst_local, src-half) sort as before.
// Gathers: R10's soft-phased register-accumulate kernels (unchanged).

constexpr int N_NODES = 100000;
constexpr int N_EDGES = 2500000;
constexpr int HALFN   = 50000;
constexpr int BUCKET  = 256;
constexpr int NBUCK   = (N_NODES + BUCKET - 1) / BUCKET;   // 391
constexpr int NBLK    = 1024;                              // build blocks
constexpr int CHUNK   = (N_EDGES + NBLK - 1) / NBLK;       // 2442
constexpr int SCAP    = 8192;                              // sortdeg LDS stage cap

// ---- build K1: per-block LDS counting sort by bucket; contiguous write ----
__global__ __launch_bounds__(256) void k_binfill(const int* __restrict__ ei,
                                                 int* __restrict__ binned,
                                                 int* __restrict__ blkbin,
                                                 int* __restrict__ locoff) {
    __shared__ int cnt[NBUCK];
    __shared__ int cur[NBUCK];
    __shared__ int sc[512];
    __shared__ int stage[CHUNK];
    int tid = threadIdx.x;
    int blk = blockIdx.x;
    int beg = blk * CHUNK;
    int end = min(beg + CHUNK, N_EDGES);
    int m = end - beg;

    for (int i = tid; i < NBUCK; i += 256) cnt[i] = 0;
    __syncthreads();
    for (int e = beg + tid; e < end; e += 256)
        atomicAdd(&cnt[ei[N_EDGES + e] >> 8], 1);
    __syncthreads();

    // exclusive scan of 391 counts (2 slots/thread Hillis-Steele over 512)
    sc[tid]       = (tid < NBUCK) ? cnt[tid] : 0;
    sc[tid + 256] = (tid + 256 < NBUCK) ? cnt[tid + 256] : 0;
    __syncthreads();
#pragma unroll
    for (int o = 1; o < 512; o <<= 1) {
        int a0 = (tid >= o) ? sc[tid - o] : 0;
        int a1 = (tid + 256 >= o) ? sc[tid + 256 - o] : 0;
        __syncthreads();
        sc[tid] += a0; sc[tid + 256] += a1;
        __syncthreads();
    }
    // emit histogram + absolute run starts; init cursors
    if (tid < NBUCK) {
        int excl = sc[tid] - cnt[tid];
        cur[tid] = excl;
        blkbin[tid * NBLK + blk] = cnt[tid];
        locoff[blk * NBUCK + tid] = beg + excl;
    }
    if (tid + 256 < NBUCK) {
        int i = tid + 256;
        int excl = sc[i] - cnt[i];
        cur[i] = excl;
        blkbin[i * NBLK + blk] = cnt[i];
        locoff[blk * NBUCK + i] = beg + excl;
    }
    __syncthreads();

    for (int e = beg + tid; e < end; e += 256) {
        int s = ei[e];
        int d = ei[N_EDGES + e];
        int pos = atomicAdd(&cur[d >> 8], 1);
        stage[pos] = (s << 8) | (d & 255);     // src<17b><<8 | dst_local<8b>
    }
    __syncthreads();
    for (int i = tid; i < m; i += 256) binned[beg + i] = stage[i];  // coalesced
}

// ---- build K2: bin totals (one wave per bin) ----
__global__ __launch_bounds__(256) void k_bintot(const int* __restrict__ blkbin,
                                                int* __restrict__ bintot) {
    int w = threadIdx.x >> 6, lane = threadIdx.x & 63;
    int bin = blockIdx.x * 4 + w;
    if (bin >= NBUCK) return;
    int s = 0;
    for (int k = lane; k < NBLK; k += 64) s += blkbin[bin * NBLK + k];
#pragma unroll
    for (int o = 32; o > 0; o >>= 1) s += __shfl_down(s, o);
    if (lane == 0) bintot[bin] = s;
}

// ---- build K3: exclusive scan of 391 bin totals -> binoff ----
__global__ __launch_bounds__(512) void k_binscan(const int* __restrict__ bintot,
                                                 int* __restrict__ binoff) {
    __shared__ int sc[512];
    int tid = threadIdx.x;
    int v = (tid < NBUCK) ? bintot[tid] : 0;
    sc[tid] = v;
    __syncthreads();
#pragma unroll
    for (int o = 1; o < 512; o <<= 1) {
        int t = (tid >= o) ? sc[tid - o] : 0;
        __syncthreads();
        sc[tid] += t;
        __syncthreads();
    }
    if (tid < NBUCK) binoff[tid] = sc[tid] - v;
    if (tid == NBUCK - 1) binoff[NBUCK] = sc[tid];
}

// ---- build K4: per-bucket 512-key sort (dst_local*2 + src-half) ----
// Assembles the bucket's 1024 runs into LDS, then hist/scan/scatter.
__global__ __launch_bounds__(512) void k_sortdeg(const int* __restrict__ binned,
                                                 const int* __restrict__ blkbin,
                                                 const int* __restrict__ locoff,
                                                 const int* __restrict__ binoff,
                                                 int* __restrict__ csr_src,
                                                 int* __restrict__ rowptr,
                                                 int* __restrict__ rowmid,
                                                 float* __restrict__ dinv) {
    __shared__ int stage[SCAP];      // 32 KB
    __shared__ int runlen[NBLK];     // 4 KB
    __shared__ int runpos[NBLK];     // 4 KB (inclusive scan)
    __shared__ int cnt[512];
    __shared__ int sc[512];
    __shared__ int cur[512];
    int t = threadIdx.x;
    int b = blockIdx.x;
    int beg = binoff[b], end = binoff[b + 1];
    int total = end - beg;
    bool fits = (total <= SCAP);

    runlen[t]       = blkbin[b * NBLK + t];
    runlen[t + 512] = blkbin[b * NBLK + t + 512];
    runpos[t] = runlen[t];
    runpos[t + 512] = runlen[t + 512];
    __syncthreads();
#pragma unroll
    for (int o = 1; o < 1024; o <<= 1) {
        int a0 = (t >= o) ? runpos[t - o] : 0;
        int a1 = (t + 512 >= o) ? runpos[t + 512 - o] : 0;
        __syncthreads();
        runpos[t] += a0; runpos[t + 512] += a1;
        __syncthreads();
    }

    cnt[t] = 0;
    __syncthreads();
    if (fits) {
        for (int blk = t; blk < NBLK; blk += 512) {
            int len = runlen[blk];
            int srcp = locoff[blk * NBUCK + b];
            int dstp = runpos[blk] - len;
            for (int i = 0; i < len; ++i) stage[dstp + i] = binned[srcp + i];
        }
        __syncthreads();
        for (int k = t; k < total; k += 512) {
            int p = stage[k];
            int key = ((p & 255) << 1) | (((p >> 8) >= HALFN) ? 1 : 0);
            atomicAdd(&cnt[key], 1);
        }
    } else {   // overflow fallback (statistically never): hist direct from global
        for (int blk = t; blk < NBLK; blk += 512) {
            int len = runlen[blk];
            int srcp = locoff[blk * NBUCK + b];
            for (int i = 0; i < len; ++i) {
                int p = binned[srcp + i];
                int key = ((p & 255) << 1) | (((p >> 8) >= HALFN) ? 1 : 0);
                atomicAdd(&cnt[key], 1);
            }
        }
    }
    __syncthreads();

    int v = cnt[t];
    sc[t] = v;
    __syncthreads();
#pragma unroll
    for (int o = 1; o < 512; o <<= 1) {
        int tv = (t >= o) ? sc[t - o] : 0;
        __syncthreads();
        sc[t] += tv;
        __syncthreads();
    }
    int excl = sc[t] - v;
    cur[t] = excl;
    int dl = t >> 1;
    int n = b * 256 + dl;
    if (n < N_NODES) {
        if ((t & 1) == 0) {
            rowptr[n] = beg + excl;
            dinv[n] = rsqrtf((float)(cnt[t] + cnt[t + 1] + 1));  // +1 self-loop
        } else {
            rowmid[n] = beg + excl;
        }
    }
    if (b == NBUCK - 1 && t == 0) rowptr[N_NODES] = end;
    __syncthreads();

    if (fits) {
        for (int k = t; k < total; k += 512) {
            int p = stage[k];
            int key = ((p & 255) << 1) | (((p >> 8) >= HALFN) ? 1 : 0);
            int pos = atomicAdd(&cur[key], 1);
            csr_src[beg + pos] = p >> 8;
        }
    } else {
        for (int blk = t; blk < NBLK; blk += 512) {
            int len = runlen[blk];
            int srcp = locoff[blk * NBUCK + b];
            for (int i = 0; i < len; ++i) {
                int p = binned[srcp + i];
                int key = ((p & 255) << 1) | (((p >> 8) >= HALFN) ? 1 : 0);
                int pos = atomicAdd(&cur[key], 1);
                csr_src[beg + pos] = p >> 8;
            }
        }
    }
}

// ================= dense helpers =================
__device__ inline void store_half8(__half* p, const float* v) {
    __half2 h[4];
#pragma unroll
    for (int i = 0; i < 4; ++i)
        h[i] = __floats2half2_rn(v[2 * i], v[2 * i + 1]);
    *(float4*)p = *(float4*)h;
}

__device__ inline void acc_half8(float* acc, float4 raw) {
    __half2* hp = (__half2*)&raw;
#pragma unroll
    for (int i = 0; i < 4; ++i) {
        float2 f = __half22float2(hp[i]);
        acc[2 * i]     += f.x;
        acc[2 * i + 1] += f.y;
    }
}

// t = relu(x@Wfc1 + bfc1); g = half( dinv * (t@Wc1) )
__global__ __launch_bounds__(256) void k_fc1_conv1(
        const float* __restrict__ x,
        const float* __restrict__ Wfc1, const float* __restrict__ bfc1,
        const float* __restrict__ Wc1, const float* __restrict__ dinv,
        __half* __restrict__ g) {
    __shared__ float  sWf[128];
    __shared__ float  sbf[32];
    __shared__ float4 sW[256];
    if (threadIdx.x < 128) sWf[threadIdx.x] = Wfc1[threadIdx.x];
    if (threadIdx.x < 32)  sbf[threadIdx.x] = bfc1[threadIdx.x];
    sW[threadIdx.x] = ((const float4*)Wc1)[threadIdx.x];
    __syncthreads();

    int n = blockIdx.x * 256 + threadIdx.x;
    if (n >= N_NODES) return;

    float4 xin = *(const float4*)(x + (size_t)n * 4);
    float t[32];
#pragma unroll
    for (int j = 0; j < 32; ++j) {
        float a = fmaf(xin.x, sWf[j], sbf[j]);
        a = fmaf(xin.y, sWf[32 + j], a);
        a = fmaf(xin.z, sWf[64 + j], a);
        a = fmaf(xin.w, sWf[96 + j], a);
        t[j] = fmaxf(a, 0.0f);
    }
    float o[32];
#pragma unroll
    for (int j = 0; j < 32; ++j) o[j] = 0.f;
#pragma unroll
    for (int k = 0; k < 32; ++k) {
        float a = t[k];
#pragma unroll
        for (int q = 0; q < 8; ++q) {
            float4 w = sW[k * 8 + q];
            o[q * 4 + 0] = fmaf(a, w.x, o[q * 4 + 0]);
            o[q * 4 + 1] = fmaf(a, w.y, o[q * 4 + 1]);
            o[q * 4 + 2] = fmaf(a, w.z, o[q * 4 + 2]);
            o[q * 4 + 3] = fmaf(a, w.w, o[q * 4 + 3]);
        }
    }
    float dv = dinv[n];
#pragma unroll
    for (int j = 0; j < 32; ++j) o[j] *= dv;
    __half* gp = g + (size_t)n * 32;
    store_half8(gp,      o);
    store_half8(gp + 8,  o + 8);
    store_half8(gp + 16, o + 16);
    store_half8(gp + 24, o + 24);
}

// ---- edge-segment accumulate, unroll x4 ----
__device__ inline void gather_seg(int beg, int end, const int* __restrict__ csr_src,
                                  const __half* __restrict__ gin, int sub, float* acc) {
    int k = beg;
    for (; k + 3 < end; k += 4) {
        int s0 = csr_src[k], s1 = csr_src[k + 1];
        int s2 = csr_src[k + 2], s3 = csr_src[k + 3];
        float4 r0 = *(const float4*)(gin + (size_t)s0 * 32 + sub * 8);
        float4 r1 = *(const float4*)(gin + (size_t)s1 * 32 + sub * 8);
        float4 r2 = *(const float4*)(gin + (size_t)s2 * 32 + sub * 8);
        float4 r3 = *(const float4*)(gin + (size_t)s3 * 32 + sub * 8);
        acc_half8(acc, r0); acc_half8(acc, r1);
        acc_half8(acc, r2); acc_half8(acc, r3);
    }
    for (; k < end; ++k) {
        int s = csr_src[k];
        float4 r = *(const float4*)(gin + (size_t)s * 32 + sub * 8);
        acc_half8(acc, r);
    }
}

// ---- soft-phased fused gather + mid MLP: 4 threads/node, 64 nodes/block ----
__global__ __launch_bounds__(256) void k_gather_mid(
        const int* __restrict__ rowptr, const int* __restrict__ rowmid,
        const int* __restrict__ csr_src, const __half* __restrict__ gin,
        const float* __restrict__ dinv,
        const float* __restrict__ b, const float* __restrict__ W,
        __half* __restrict__ gout) {
    __shared__ float sS[64 * 33];
    __shared__ float sW[1024];
    __shared__ float sb[32];
    for (int i = threadIdx.x; i < 1024; i += 256) sW[i] = W[i];
    if (threadIdx.x < 32) sb[threadIdx.x] = b[threadIdx.x];

    int nl = threadIdx.x >> 2;
    int sub = threadIdx.x & 3;
    int n = blockIdx.x * 64 + nl;
    float acc[8];
    if (n < N_NODES) {
        float4 self = *(const float4*)(gin + (size_t)n * 32 + sub * 8);
        {
            __half2* hp = (__half2*)&self;
#pragma unroll
            for (int i = 0; i < 4; ++i) {
                float2 f = __half22float2(hp[i]);
                acc[2 * i] = f.x;
                acc[2 * i + 1] = f.y;
            }
        }
        int beg = rowptr[n], mid = rowmid[n], end = rowptr[n + 1];
        gather_seg(beg, mid, csr_src, gin, sub, acc);   // phase A: src < 50K
        gather_seg(mid, end, csr_src, gin, sub, acc);   // phase B: src >= 50K
#pragma unroll
        for (int i = 0; i < 8; ++i) sS[nl * 33 + sub * 8 + i] = acc[i];
    }
    __syncthreads();

    if (n >= N_NODES) return;
    float dv = dinv[n];
    float t[32];
#pragma unroll
    for (int kk = 0; kk < 32; ++kk)
        t[kk] = fmaxf(fmaf(dv, sS[nl * 33 + kk], sb[kk]), 0.0f);
    float o[8];
#pragma unroll
    for (int j = 0; j < 8; ++j) o[j] = 0.f;
#pragma unroll
    for (int kk = 0; kk < 32; ++kk) {
        float a = t[kk];
#pragma unroll
        for (int j = 0; j < 8; ++j)
            o[j] = fmaf(a, sW[kk * 32 + sub * 8 + j], o[j]);
    }
#pragma unroll
    for (int j = 0; j < 8; ++j) o[j] *= dv;
    store_half8(gout + (size_t)n * 32 + sub * 8, o);
}

// ---- soft-phased fused gather + final layer ----
__global__ __launch_bounds__(256) void k_gather_out(
        const int* __restrict__ rowptr, const int* __restrict__ rowmid,
        const int* __restrict__ csr_src, const __half* __restrict__ gin,
        const float* __restrict__ dinv,
        const float* __restrict__ bc3, const float* __restrict__ Wfc2,
        const float* __restrict__ bfc2, float* __restrict__ out) {
    __shared__ float sS[64 * 33];
    __shared__ float sW[96];
    __shared__ float sb[32];
    __shared__ float sb2[3];
    if (threadIdx.x < 96) sW[threadIdx.x] = Wfc2[threadIdx.x];
    if (threadIdx.x < 32) sb[threadIdx.x] = bc3[threadIdx.x];
    if (threadIdx.x < 3)  sb2[threadIdx.x] = bfc2[threadIdx.x];

    int nl = threadIdx.x >> 2;
    int sub = threadIdx.x & 3;
    int n = blockIdx.x * 64 + nl;
    float acc[8];
    if (n < N_NODES) {
        float4 self = *(const float4*)(gin + (size_t)n * 32 + sub * 8);
        {
            __half2* hp = (__half2*)&self;
#pragma unroll
            for (int i = 0; i < 4; ++i) {
                float2 f = __half22float2(hp[i]);
                acc[2 * i] = f.x;
                acc[2 * i + 1] = f.y;
            }
        }
        int beg = rowptr[n], mid = rowmid[n], end = rowptr[n + 1];
        gather_seg(beg, mid, csr_src, gin, sub, acc);
        gather_seg(mid, end, csr_src, gin, sub, acc);
#pragma unroll
        for (int i = 0; i < 8; ++i) sS[nl * 33 + sub * 8 + i] = acc[i];
    }
    __syncthreads();

    if (n >= N_NODES || sub != 0) return;
    float dv = dinv[n];
    float t[32];
#pragma unroll
    for (int kk = 0; kk < 32; ++kk)
        t[kk] = fmaxf(fmaf(dv, sS[nl * 33 + kk], sb[kk]), 0.0f);
    float o0 = sb2[0], o1 = sb2[1], o2 = sb2[2];
#pragma unroll
    for (int kk = 0; kk < 32; ++kk) {
        o0 = fmaf(t[kk], sW[kk * 3 + 0], o0);
        o1 = fmaf(t[kk], sW[kk * 3 + 1], o1);
        o2 = fmaf(t[kk], sW[kk * 3 + 2], o2);
    }
    out[(size_t)n * 3 + 0] = o0;
    out[(size_t)n * 3 + 1] = o1;
    out[(size_t)n * 3 + 2] = o2;
}

extern "C" void kernel_launch(void* const* d_in, const int* in_sizes, int n_in,
                              void* d_out, int out_size, void* d_ws, size_t ws_size,
                              hipStream_t stream) {
    const float* x    = (const float*)d_in[0];
    const int*   ei   = (const int*)d_in[1];
    const float* Wfc1 = (const float*)d_in[2];
    const float* bfc1 = (const float*)d_in[3];
    const float* Wc1  = (const float*)d_in[4];
    const float* bc1  = (const float*)d_in[5];
    const float* Wc2  = (const float*)d_in[6];
    const float* bc2  = (const float*)d_in[7];
    const float* Wc3  = (const float*)d_in[8];
    const float* bc3  = (const float*)d_in[9];
    const float* Wfc2 = (const float*)d_in[10];
    const float* bfc2 = (const float*)d_in[11];
    float* out = (float*)d_out;

    char* ws = (char*)d_ws;
    const size_t grow = (size_t)N_NODES * 32 * sizeof(__half);   // 6.4 MB
    size_t off = 0;
    __half* gA     = (__half*)(ws + off); off += grow;
    __half* gB     = (__half*)(ws + off); off += grow;
    int*   binned  = (int*)  (ws + off); off += (size_t)NBLK * CHUNK * sizeof(int);
    int*   csr_src = (int*)  (ws + off); off += (size_t)N_EDGES * sizeof(int);
    float* dinv    = (float*)(ws + off); off += (size_t)N_NODES * sizeof(float);
    int*   rowptr  = (int*)  (ws + off); off += (size_t)(N_NODES + 1) * sizeof(int);
    int*   rowmid  = (int*)  (ws + off); off += (size_t)N_NODES * sizeof(int);
    int*   blkbin  = (int*)  (ws + off); off += (size_t)NBUCK * NBLK * sizeof(int);
    int*   locoff  = (int*)  (ws + off); off += (size_t)NBLK * NBUCK * sizeof(int);
    int*   bintot  = (int*)  (ws + off); off += (size_t)NBUCK * sizeof(int);
    int*   binoff  = (int*)  (ws + off); off += (size_t)(NBUCK + 1) * sizeof(int);

    const int nb_wave = (NBUCK + 3) / 4;              // 98
    const int nb_n = (N_NODES + 255) / 256;           // 391
    const int nb_f = (N_NODES * 4 + 255) / 256;       // 1563 (4 thr/node)

    k_binfill<<<NBLK, 256, 0, stream>>>(ei, binned, blkbin, locoff);
    k_bintot<<<nb_wave, 256, 0, stream>>>(blkbin, bintot);
    k_binscan<<<1, 512, 0, stream>>>(bintot, binoff);
    k_sortdeg<<<NBUCK, 512, 0, stream>>>(binned, blkbin, locoff, binoff,
                                         csr_src, rowptr, rowmid, dinv);

    k_fc1_conv1<<<nb_n, 256, 0, stream>>>(x, Wfc1, bfc1, Wc1, dinv, gA);
    k_gather_mid<<<nb_f, 256, 0, stream>>>(rowptr, rowmid, csr_src, gA, dinv, bc1, Wc2, gB);
    k_gather_mid<<<nb_f, 256, 0, stream>>>(rowptr, rowmid, csr_src, gB, dinv, bc2, Wc3, gA);
    k_gather_out<<<nb_f, 256, 0, stream>>>(rowptr, rowmid, csr_src, gA, dinv, bc3, Wfc2, bfc2, out);
}

// Round 12
// 233.092 us; speedup vs baseline: 1.3543x; 1.0332x over previous
//
#include <hip/hip_runtime.h>
#include <hip/hip_fp16.h>

// GCN: 100K nodes, 2.5M edges, dims 4 -> 32 -> (32x32 conv x3) -> 3.
// Round 12: (a) k_binwave fuses bin totals + per-bin run-placement prefix
// (old k_blkoff) so k_sortdeg drops its 1024-wide LDS scan (20 barriers/blk);
// (b) gather_seg software-pipelines: prefetch next 4 indices before
// accumulating current 4 rows (gathers are latency-bound, VALUBusy ~9%).
// Rest = R11: scatter-free block-major build, fp16 g, soft-phased gathers
// with fused MLP epilogues, fp32 accumulate.

constexpr int N_NODES = 100000;
constexpr int N_EDGES = 2500000;
constexpr int HALFN   = 50000;
constexpr int BUCKET  = 256;
constexpr int NBUCK   = (N_NODES + BUCKET - 1) / BUCKET;   // 391
constexpr int NBLK    = 1024;                              // build blocks
constexpr int CHUNK   = (N_EDGES + NBLK - 1) / NBLK;       // 2442
constexpr int SCAP    = 8192;                              // sortdeg LDS stage cap
constexpr int PERLANE = NBLK / 64;                         // 16

// ---- build K1: per-block LDS counting sort by bucket; contiguous write ----
__global__ __launch_bounds__(256) void k_binfill(const int* __restrict__ ei,
                                                 int* __restrict__ binned,
                                                 int* __restrict__ blkbin,
                                                 int* __restrict__ locoff) {
    __shared__ int cnt[NBUCK];
    __shared__ int cur[NBUCK];
    __shared__ int sc[512];
    __shared__ int stage[CHUNK];
    int tid = threadIdx.x;
    int blk = blockIdx.x;
    int beg = blk * CHUNK;
    int end = min(beg + CHUNK, N_EDGES);
    int m = end - beg;

    for (int i = tid; i < NBUCK; i += 256) cnt[i] = 0;
    __syncthreads();
    for (int e = beg + tid; e < end; e += 256)
        atomicAdd(&cnt[ei[N_EDGES + e] >> 8], 1);
    __syncthreads();

    // exclusive scan of 391 counts (2 slots/thread Hillis-Steele over 512)
    sc[tid]       = (tid < NBUCK) ? cnt[tid] : 0;
    sc[tid + 256] = (tid + 256 < NBUCK) ? cnt[tid + 256] : 0;
    __syncthreads();
#pragma unroll
    for (int o = 1; o < 512; o <<= 1) {
        int a0 = (tid >= o) ? sc[tid - o] : 0;
        int a1 = (tid + 256 >= o) ? sc[tid + 256 - o] : 0;
        __syncthreads();
        sc[tid] += a0; sc[tid + 256] += a1;
        __syncthreads();
    }
    if (tid < NBUCK) {
        int excl = sc[tid] - cnt[tid];
        cur[tid] = excl;
        blkbin[tid * NBLK + blk] = cnt[tid];
        locoff[blk * NBUCK + tid] = beg + excl;
    }
    if (tid + 256 < NBUCK) {
        int i = tid + 256;
        int excl = sc[i] - cnt[i];
        cur[i] = excl;
        blkbin[i * NBLK + blk] = cnt[i];
        locoff[blk * NBUCK + i] = beg + excl;
    }
    __syncthreads();

    for (int e = beg + tid; e < end; e += 256) {
        int s = ei[e];
        int d = ei[N_EDGES + e];
        int pos = atomicAdd(&cur[d >> 8], 1);
        stage[pos] = (s << 8) | (d & 255);     // src<17b><<8 | dst_local<8b>
    }
    __syncthreads();
    for (int i = tid; i < m; i += 256) binned[beg + i] = stage[i];  // coalesced
}

// ---- build K2: per-bin total + per-bin run-placement prefix (one wave/bin) ----
__global__ __launch_bounds__(256) void k_binwave(const int* __restrict__ blkbin,
                                                 int* __restrict__ bintot,
                                                 int* __restrict__ blkpos) {
    int w = threadIdx.x >> 6, lane = threadIdx.x & 63;
    int bin = blockIdx.x * 4 + w;
    if (bin >= NBUCK) return;
    int v[PERLANE];
#pragma unroll
    for (int i = 0; i < PERLANE; ++i) v[i] = blkbin[bin * NBLK + lane * PERLANE + i];
    int mysum = 0;
#pragma unroll
    for (int i = 0; i < PERLANE; ++i) mysum += v[i];
    int pre = mysum;
#pragma unroll
    for (int o = 1; o < 64; o <<= 1) {
        int t = __shfl_up(pre, o);
        if (lane >= o) pre += t;
    }
    int excl = pre - mysum;                    // exclusive across lanes
    int run = excl;
#pragma unroll
    for (int i = 0; i < PERLANE; ++i) {
        blkpos[bin * NBLK + lane * PERLANE + i] = run;   // bucket-local run start
        run += v[i];
    }
    if (lane == 63) bintot[bin] = pre;         // inclusive over all = total
}

// ---- build K3: exclusive scan of 391 bin totals -> binoff ----
__global__ __launch_bounds__(512) void k_binscan(const int* __restrict__ bintot,
                                                 int* __restrict__ binoff) {
    __shared__ int sc[512];
    int tid = threadIdx.x;
    int v = (tid < NBUCK) ? bintot[tid] : 0;
    sc[tid] = v;
    __syncthreads();
#pragma unroll
    for (int o = 1; o < 512; o <<= 1) {
        int t = (tid >= o) ? sc[tid - o] : 0;
        __syncthreads();
        sc[tid] += t;
        __syncthreads();
    }
    if (tid < NBUCK) binoff[tid] = sc[tid] - v;
    if (tid == NBUCK - 1) binoff[NBUCK] = sc[tid];
}

// ---- build K4: per-bucket 512-key sort (dst_local*2 + src-half) ----
__global__ __launch_bounds__(512) void k_sortdeg(const int* __restrict__ binned,
                                                 const int* __restrict__ blkbin,
                                                 const int* __restrict__ blkpos,
                                                 const int* __restrict__ locoff,
                                                 const int* __restrict__ binoff,
                                                 int* __restrict__ csr_src,
                                                 int* __restrict__ rowptr,
                                                 int* __restrict__ rowmid,
                                                 float* __restrict__ dinv) {
    __shared__ int stage[SCAP];      // 32 KB
    __shared__ int runlen[NBLK];     // 4 KB
    __shared__ int runpos[NBLK];     // 4 KB (bucket-local starts, precomputed)
    __shared__ int cnt[512];
    __shared__ int sc[512];
    __shared__ int cur[512];
    int t = threadIdx.x;
    int b = blockIdx.x;
    int beg = binoff[b], end = binoff[b + 1];
    int total = end - beg;
    bool fits = (total <= SCAP);

    runlen[t]       = blkbin[b * NBLK + t];
    runlen[t + 512] = blkbin[b * NBLK + t + 512];
    runpos[t]       = blkpos[b * NBLK + t];
    runpos[t + 512] = blkpos[b * NBLK + t + 512];
    cnt[t] = 0;
    __syncthreads();

    if (fits) {
        for (int blk = t; blk < NBLK; blk += 512) {
            int len = runlen[blk];
            int srcp = locoff[blk * NBUCK + b];
            int dstp = runpos[blk];
            for (int i = 0; i < len; ++i) stage[dstp + i] = binned[srcp + i];
        }
        __syncthreads();
        for (int k = t; k < total; k += 512) {
            int p = stage[k];
            int key = ((p & 255) << 1) | (((p >> 8) >= HALFN) ? 1 : 0);
            atomicAdd(&cnt[key], 1);
        }
    } else {   // overflow fallback (statistically never)
        for (int blk = t; blk < NBLK; blk += 512) {
            int len = runlen[blk];
            int srcp = locoff[blk * NBUCK + b];
            for (int i = 0; i < len; ++i) {
                int p = binned[srcp + i];
                int key = ((p & 255) << 1) | (((p >> 8) >= HALFN) ? 1 : 0);
                atomicAdd(&cnt[key], 1);
            }
        }
    }
    __syncthreads();

    int v = cnt[t];
    sc[t] = v;
    __syncthreads();
#pragma unroll
    for (int o = 1; o < 512; o <<= 1) {
        int tv = (t >= o) ? sc[t - o] : 0;
        __syncthreads();
        sc[t] += tv;
        __syncthreads();
    }
    int excl = sc[t] - v;
    cur[t] = excl;
    int dl = t >> 1;
    int n = b * 256 + dl;
    if (n < N_NODES) {
        if ((t & 1) == 0) {
            rowptr[n] = beg + excl;
            dinv[n] = rsqrtf((float)(cnt[t] + cnt[t + 1] + 1));  // +1 self-loop
        } else {
            rowmid[n] = beg + excl;
        }
    }
    if (b == NBUCK - 1 && t == 0) rowptr[N_NODES] = end;
    __syncthreads();

    if (fits) {
        for (int k = t; k < total; k += 512) {
            int p = stage[k];
            int key = ((p & 255) << 1) | (((p >> 8) >= HALFN) ? 1 : 0);
            int pos = atomicAdd(&cur[key], 1);
            csr_src[beg + pos] = p >> 8;
        }
    } else {
        for (int blk = t; blk < NBLK; blk += 512) {
            int len = runlen[blk];
            int srcp = locoff[blk * NBUCK + b];
            for (int i = 0; i < len; ++i) {
                int p = binned[srcp + i];
                int key = ((p & 255) << 1) | (((p >> 8) >= HALFN) ? 1 : 0);
                int pos = atomicAdd(&cur[key], 1);
                csr_src[beg + pos] = p >> 8;
            }
        }
    }
}

// ================= dense helpers =================
__device__ inline void store_half8(__half* p, const float* v) {
    __half2 h[4];
#pragma unroll
    for (int i = 0; i < 4; ++i)
        h[i] = __floats2half2_rn(v[2 * i], v[2 * i + 1]);
    *(float4*)p = *(float4*)h;
}

__device__ inline void acc_half8(float* acc, float4 raw) {
    __half2* hp = (__half2*)&raw;
#pragma unroll
    for (int i = 0; i < 4; ++i) {
        float2 f = __half22float2(hp[i]);
        acc[2 * i]     += f.x;
        acc[2 * i + 1] += f.y;
    }
}

// t = relu(x@Wfc1 + bfc1); g = half( dinv * (t@Wc1) )
__global__ __launch_bounds__(256) void k_fc1_conv1(
        const float* __restrict__ x,
        const float* __restrict__ Wfc1, const float* __restrict__ bfc1,
        const float* __restrict__ Wc1, const float* __restrict__ dinv,
        __half* __restrict__ g) {
    __shared__ float  sWf[128];
    __shared__ float  sbf[32];
    __shared__ float4 sW[256];
    if (threadIdx.x < 128) sWf[threadIdx.x] = Wfc1[threadIdx.x];
    if (threadIdx.x < 32)  sbf[threadIdx.x] = bfc1[threadIdx.x];
    sW[threadIdx.x] = ((const float4*)Wc1)[threadIdx.x];
    __syncthreads();

    int n = blockIdx.x * 256 + threadIdx.x;
    if (n >= N_NODES) return;

    float4 xin = *(const float4*)(x + (size_t)n * 4);
    float t[32];
#pragma unroll
    for (int j = 0; j < 32; ++j) {
        float a = fmaf(xin.x, sWf[j], sbf[j]);
        a = fmaf(xin.y, sWf[32 + j], a);
        a = fmaf(xin.z, sWf[64 + j], a);
        a = fmaf(xin.w, sWf[96 + j], a);
        t[j] = fmaxf(a, 0.0f);
    }
    float o[32];
#pragma unroll
    for (int j = 0; j < 32; ++j) o[j] = 0.f;
#pragma unroll
    for (int k = 0; k < 32; ++k) {
        float a = t[k];
#pragma unroll
        for (int q = 0; q < 8; ++q) {
            float4 w = sW[k * 8 + q];
            o[q * 4 + 0] = fmaf(a, w.x, o[q * 4 + 0]);
            o[q * 4 + 1] = fmaf(a, w.y, o[q * 4 + 1]);
            o[q * 4 + 2] = fmaf(a, w.z, o[q * 4 + 2]);
            o[q * 4 + 3] = fmaf(a, w.w, o[q * 4 + 3]);
        }
    }
    float dv = dinv[n];
#pragma unroll
    for (int j = 0; j < 32; ++j) o[j] *= dv;
    __half* gp = g + (size_t)n * 32;
    store_half8(gp,      o);
    store_half8(gp + 8,  o + 8);
    store_half8(gp + 16, o + 16);
    store_half8(gp + 24, o + 24);
}

// ---- edge-segment accumulate: software-pipelined (prefetch next 4 indices) ----
__device__ inline void gather_seg(int beg, int end, const int* __restrict__ csr_src,
                                  const __half* __restrict__ gin, int sub, float* acc) {
    int k = beg;
    int stop = beg + ((end - beg) & ~3);
    if (k < stop) {
        int s0 = csr_src[k], s1 = csr_src[k + 1];
        int s2 = csr_src[k + 2], s3 = csr_src[k + 3];
        k += 4;
        while (k < stop) {
            float4 r0 = *(const float4*)(gin + (size_t)s0 * 32 + sub * 8);
            float4 r1 = *(const float4*)(gin + (size_t)s1 * 32 + sub * 8);
            float4 r2 = *(const float4*)(gin + (size_t)s2 * 32 + sub * 8);
            float4 r3 = *(const float4*)(gin + (size_t)s3 * 32 + sub * 8);
            s0 = csr_src[k]; s1 = csr_src[k + 1];
            s2 = csr_src[k + 2]; s3 = csr_src[k + 3];
            acc_half8(acc, r0); acc_half8(acc, r1);
            acc_half8(acc, r2); acc_half8(acc, r3);
            k += 4;
        }
        float4 r0 = *(const float4*)(gin + (size_t)s0 * 32 + sub * 8);
        float4 r1 = *(const float4*)(gin + (size_t)s1 * 32 + sub * 8);
        float4 r2 = *(const float4*)(gin + (size_t)s2 * 32 + sub * 8);
        float4 r3 = *(const float4*)(gin + (size_t)s3 * 32 + sub * 8);
        acc_half8(acc, r0); acc_half8(acc, r1);
        acc_half8(acc, r2); acc_half8(acc, r3);
    }
    for (; k < end; ++k) {
        int s = csr_src[k];
        float4 r = *(const float4*)(gin + (size_t)s * 32 + sub * 8);
        acc_half8(acc, r);
    }
}

// ---- soft-phased fused gather + mid MLP: 4 threads/node, 64 nodes/block ----
__global__ __launch_bounds__(256) void k_gather_mid(
        const int* __restrict__ rowptr, const int* __restrict__ rowmid,
        const int* __restrict__ csr_src, const __half* __restrict__ gin,
        const float* __restrict__ dinv,
        const float* __restrict__ b, const float* __restrict__ W,
        __half* __restrict__ gout) {
    __shared__ float sS[64 * 33];
    __shared__ float sW[1024];
    __shared__ float sb[32];
    for (int i = threadIdx.x; i < 1024; i += 256) sW[i] = W[i];
    if (threadIdx.x < 32) sb[threadIdx.x] = b[threadIdx.x];

    int nl = threadIdx.x >> 2;
    int sub = threadIdx.x & 3;
    int n = blockIdx.x * 64 + nl;
    float acc[8];
    if (n < N_NODES) {
        float4 self = *(const float4*)(gin + (size_t)n * 32 + sub * 8);
        {
            __half2* hp = (__half2*)&self;
#pragma unroll
            for (int i = 0; i < 4; ++i) {
                float2 f = __half22float2(hp[i]);
                acc[2 * i] = f.x;
                acc[2 * i + 1] = f.y;
            }
        }
        int beg = rowptr[n], mid = rowmid[n], end = rowptr[n + 1];
        gather_seg(beg, mid, csr_src, gin, sub, acc);   // phase A: src < 50K
        gather_seg(mid, end, csr_src, gin, sub, acc);   // phase B: src >= 50K
#pragma unroll
        for (int i = 0; i < 8; ++i) sS[nl * 33 + sub * 8 + i] = acc[i];
    }
    __syncthreads();

    if (n >= N_NODES) return;
    float dv = dinv[n];
    float t[32];
#pragma unroll
    for (int kk = 0; kk < 32; ++kk)
        t[kk] = fmaxf(fmaf(dv, sS[nl * 33 + kk], sb[kk]), 0.0f);
    float o[8];
#pragma unroll
    for (int j = 0; j < 8; ++j) o[j] = 0.f;
#pragma unroll
    for (int kk = 0; kk < 32; ++kk) {
        float a = t[kk];
#pragma unroll
        for (int j = 0; j < 8; ++j)
            o[j] = fmaf(a, sW[kk * 32 + sub * 8 + j], o[j]);
    }
#pragma unroll
    for (int j = 0; j < 8; ++j) o[j] *= dv;
    store_half8(gout + (size_t)n * 32 + sub * 8, o);
}

// ---- soft-phased fused gather + final layer ----
__global__ __launch_bounds__(256) void k_gather_out(
        const int* __restrict__ rowptr, const int* __restrict__ rowmid,
        const int* __restrict__ csr_src, const __half* __restrict__ gin,
        const float* __restrict__ dinv,
        const float* __restrict__ bc3, const float* __restrict__ Wfc2,
        const float* __restrict__ bfc2, float* __restrict__ out) {
    __shared__ float sS[64 * 33];
    __shared__ float sW[96];
    __shared__ float sb[32];
    __shared__ float sb2[3];
    if (threadIdx.x < 96) sW[threadIdx.x] = Wfc2[threadIdx.x];
    if (threadIdx.x < 32) sb[threadIdx.x] = bc3[threadIdx.x];
    if (threadIdx.x < 3)  sb2[threadIdx.x] = bfc2[threadIdx.x];

    int nl = threadIdx.x >> 2;
    int sub = threadIdx.x & 3;
    int n = blockIdx.x * 64 + nl;
    float acc[8];
    if (n < N_NODES) {
        float4 self = *(const float4*)(gin + (size_t)n * 32 + sub * 8);
        {
            __half2* hp = (__half2*)&self;
#pragma unroll
            for (int i = 0; i < 4; ++i) {
                float2 f = __half22float2(hp[i]);
                acc[2 * i] = f.x;
                acc[2 * i + 1] = f.y;
            }
        }
        int beg = rowptr[n], mid = rowmid[n], end = rowptr[n + 1];
        gather_seg(beg, mid, csr_src, gin, sub, acc);
        gather_seg(mid, end, csr_src, gin, sub, acc);
#pragma unroll
        for (int i = 0; i < 8; ++i) sS[nl * 33 + sub * 8 + i] = acc[i];
    }
    __syncthreads();

    if (n >= N_NODES || sub != 0) return;
    float dv = dinv[n];
    float t[32];
#pragma unroll
    for (int kk = 0; kk < 32; ++kk)
        t[kk] = fmaxf(fmaf(dv, sS[nl * 33 + kk], sb[kk]), 0.0f);
    float o0 = sb2[0], o1 = sb2[1], o2 = sb2[2];
#pragma unroll
    for (int kk = 0; kk < 32; ++kk) {
        o0 = fmaf(t[kk], sW[kk * 3 + 0], o0);
        o1 = fmaf(t[kk], sW[kk * 3 + 1], o1);
        o2 = fmaf(t[kk], sW[kk * 3 + 2], o2);
    }
    out[(size_t)n * 3 + 0] = o0;
    out[(size_t)n * 3 + 1] = o1;
    out[(size_t)n * 3 + 2] = o2;
}

extern "C" void kernel_launch(void* const* d_in, const int* in_sizes, int n_in,
                              void* d_out, int out_size, void* d_ws, size_t ws_size,
                              hipStream_t stream) {
    const float* x    = (const float*)d_in[0];
    const int*   ei   = (const int*)d_in[1];
    const float* Wfc1 = (const float*)d_in[2];
    const float* bfc1 = (const float*)d_in[3];
    const float* Wc1  = (const float*)d_in[4];
    const float* bc1  = (const float*)d_in[5];
    const float* Wc2  = (const float*)d_in[6];
    const float* bc2  = (const float*)d_in[7];
    const float* Wc3  = (const float*)d_in[8];
    const float* bc3  = (const float*)d_in[9];
    const float* Wfc2 = (const float*)d_in[10];
    const float* bfc2 = (const float*)d_in[11];
    float* out = (float*)d_out;

    char* ws = (char*)d_ws;
    const size_t grow = (size_t)N_NODES * 32 * sizeof(__half);   // 6.4 MB
    size_t off = 0;
    __half* gA     = (__half*)(ws + off); off += grow;
    __half* gB     = (__half*)(ws + off); off += grow;
    int*   binned  = (int*)  (ws + off); off += (size_t)NBLK * CHUNK * sizeof(int);
    int*   csr_src = (int*)  (ws + off); off += (size_t)N_EDGES * sizeof(int);
    float* dinv    = (float*)(ws + off); off += (size_t)N_NODES * sizeof(float);
    int*   rowptr  = (int*)  (ws + off); off += (size_t)(N_NODES + 1) * sizeof(int);
    int*   rowmid  = (int*)  (ws + off); off += (size_t)N_NODES * sizeof(int);
    int*   blkbin  = (int*)  (ws + off); off += (size_t)NBUCK * NBLK * sizeof(int);
    int*   blkpos  = (int*)  (ws + off); off += (size_t)NBUCK * NBLK * sizeof(int);
    int*   locoff  = (int*)  (ws + off); off += (size_t)NBLK * NBUCK * sizeof(int);
    int*   bintot  = (int*)  (ws + off); off += (size_t)NBUCK * sizeof(int);
    int*   binoff  = (int*)  (ws + off); off += (size_t)(NBUCK + 1) * sizeof(int);

    const int nb_wave = (NBUCK + 3) / 4;              // 98
    const int nb_n = (N_NODES + 255) / 256;           // 391
    const int nb_f = (N_NODES * 4 + 255) / 256;       // 1563 (4 thr/node)

    k_binfill<<<NBLK, 256, 0, stream>>>(ei, binned, blkbin, locoff);
    k_binwave<<<nb_wave, 256, 0, stream>>>(blkbin, bintot, blkpos);
    k_binscan<<<1, 512, 0, stream>>>(bintot, binoff);
    k_sortdeg<<<NBUCK, 512, 0, stream>>>(binned, blkbin, blkpos, locoff, binoff,
                                         csr_src, rowptr, rowmid, dinv);

    k_fc1_conv1<<<nb_n, 256, 0, stream>>>(x, Wfc1, bfc1, Wc1, dinv, gA);
    k_gather_mid<<<nb_f, 256, 0, stream>>>(rowptr, rowmid, csr_src, gA, dinv, bc1, Wc2, gB);
    k_gather_mid<<<nb_f, 256, 0, stream>>>(rowptr, rowmid, csr_src, gB, dinv, bc2, Wc3, gA);
    k_gather_out<<<nb_f, 256, 0, stream>>>(rowptr, rowmid, csr_src, gA, dinv, bc3, Wfc2, bfc2, out);
}

// Round 13
// 227.427 us; speedup vs baseline: 1.3880x; 1.0249x over previous
//
#include <hip/hip_runtime.h>
#include <hip/hip_fp16.h>

// GCN: 100K nodes, 2.5M edges, dims 4 -> 32 -> (32x32 conv x3) -> 3.
// Round 13: 4-PHASE soft gather. Sort key = dst_local*4 + src_quad
// (quad = src/25000), per-node segments in rowseg[N][4] (+sentinel). Gather
// walks the 4 segments in order: per-phase hot set = 1.6MB (L2-resident incl.
// streams). R10's 2-phase soft split gave -26us; this tightens the window.
// Rest = R12: scatter-free block-major build, binwave-precomputed run
// placement, fp16 g, software-pipelined gather, fused MLP epilogues.

constexpr int N_NODES = 100000;
constexpr int N_EDGES = 2500000;
constexpr int QDIV    = 25000;                             // src quad divisor
constexpr int BUCKET  = 256;
constexpr int NBUCK   = (N_NODES + BUCKET - 1) / BUCKET;   // 391
constexpr int NBLK    = 1024;                              // build blocks
constexpr int CHUNK   = (N_EDGES + NBLK - 1) / NBLK;       // 2442
constexpr int SCAP    = 8192;                              // sortdeg LDS stage cap
constexpr int PERLANE = NBLK / 64;                         // 16

// ---- build K1: per-block LDS counting sort by bucket; contiguous write ----
__global__ __launch_bounds__(256) void k_binfill(const int* __restrict__ ei,
                                                 int* __restrict__ binned,
                                                 int* __restrict__ blkbin,
                                                 int* __restrict__ locoff) {
    __shared__ int cnt[NBUCK];
    __shared__ int cur[NBUCK];
    __shared__ int sc[512];
    __shared__ int stage[CHUNK];
    int tid = threadIdx.x;
    int blk = blockIdx.x;
    int beg = blk * CHUNK;
    int end = min(beg + CHUNK, N_EDGES);
    int m = end - beg;

    for (int i = tid; i < NBUCK; i += 256) cnt[i] = 0;
    __syncthreads();
    for (int e = beg + tid; e < end; e += 256)
        atomicAdd(&cnt[ei[N_EDGES + e] >> 8], 1);
    __syncthreads();

    sc[tid]       = (tid < NBUCK) ? cnt[tid] : 0;
    sc[tid + 256] = (tid + 256 < NBUCK) ? cnt[tid + 256] : 0;
    __syncthreads();
#pragma unroll
    for (int o = 1; o < 512; o <<= 1) {
        int a0 = (tid >= o) ? sc[tid - o] : 0;
        int a1 = (tid + 256 >= o) ? sc[tid + 256 - o] : 0;
        __syncthreads();
        sc[tid] += a0; sc[tid + 256] += a1;
        __syncthreads();
    }
    if (tid < NBUCK) {
        int excl = sc[tid] - cnt[tid];
        cur[tid] = excl;
        blkbin[tid * NBLK + blk] = cnt[tid];
        locoff[blk * NBUCK + tid] = beg + excl;
    }
    if (tid + 256 < NBUCK) {
        int i = tid + 256;
        int excl = sc[i] - cnt[i];
        cur[i] = excl;
        blkbin[i * NBLK + blk] = cnt[i];
        locoff[blk * NBUCK + i] = beg + excl;
    }
    __syncthreads();

    for (int e = beg + tid; e < end; e += 256) {
        int s = ei[e];
        int d = ei[N_EDGES + e];
        int pos = atomicAdd(&cur[d >> 8], 1);
        stage[pos] = (s << 8) | (d & 255);     // src<17b><<8 | dst_local<8b>
    }
    __syncthreads();
    for (int i = tid; i < m; i += 256) binned[beg + i] = stage[i];  // coalesced
}

// ---- build K2: per-bin total + per-bin run-placement prefix (one wave/bin) ----
__global__ __launch_bounds__(256) void k_binwave(const int* __restrict__ blkbin,
                                                 int* __restrict__ bintot,
                                                 int* __restrict__ blkpos) {
    int w = threadIdx.x >> 6, lane = threadIdx.x & 63;
    int bin = blockIdx.x * 4 + w;
    if (bin >= NBUCK) return;
    int v[PERLANE];
#pragma unroll
    for (int i = 0; i < PERLANE; ++i) v[i] = blkbin[bin * NBLK + lane * PERLANE + i];
    int mysum = 0;
#pragma unroll
    for (int i = 0; i < PERLANE; ++i) mysum += v[i];
    int pre = mysum;
#pragma unroll
    for (int o = 1; o < 64; o <<= 1) {
        int t = __shfl_up(pre, o);
        if (lane >= o) pre += t;
    }
    int excl = pre - mysum;
    int run = excl;
#pragma unroll
    for (int i = 0; i < PERLANE; ++i) {
        blkpos[bin * NBLK + lane * PERLANE + i] = run;
        run += v[i];
    }
    if (lane == 63) bintot[bin] = pre;
}

// ---- build K3: exclusive scan of 391 bin totals -> binoff ----
__global__ __launch_bounds__(512) void k_binscan(const int* __restrict__ bintot,
                                                 int* __restrict__ binoff) {
    __shared__ int sc[512];
    int tid = threadIdx.x;
    int v = (tid < NBUCK) ? bintot[tid] : 0;
    sc[tid] = v;
    __syncthreads();
#pragma unroll
    for (int o = 1; o < 512; o <<= 1) {
        int t = (tid >= o) ? sc[tid - o] : 0;
        __syncthreads();
        sc[tid] += t;
        __syncthreads();
    }
    if (tid < NBUCK) binoff[tid] = sc[tid] - v;
    if (tid == NBUCK - 1) binoff[NBUCK] = sc[tid];
}

// ---- build K4: per-bucket 1024-key sort (dst_local*4 + src_quad) ----
__global__ __launch_bounds__(512) void k_sortdeg(const int* __restrict__ binned,
                                                 const int* __restrict__ blkbin,
                                                 const int* __restrict__ blkpos,
                                                 const int* __restrict__ locoff,
                                                 const int* __restrict__ binoff,
                                                 int* __restrict__ csr_src,
                                                 int* __restrict__ rowseg,
                                                 float* __restrict__ dinv) {
    __shared__ int stage[SCAP];      // 32 KB
    __shared__ int runlen[NBLK];     // 4 KB
    __shared__ int runpos[NBLK];     // 4 KB
    __shared__ int cnt[1024];        // 4 KB
    __shared__ int sc[1024];         // 4 KB
    __shared__ int cur[1024];        // 4 KB
    int t = threadIdx.x;
    int b = blockIdx.x;
    int beg = binoff[b], end = binoff[b + 1];
    int total = end - beg;
    bool fits = (total <= SCAP);

    runlen[t]       = blkbin[b * NBLK + t];
    runlen[t + 512] = blkbin[b * NBLK + t + 512];
    runpos[t]       = blkpos[b * NBLK + t];
    runpos[t + 512] = blkpos[b * NBLK + t + 512];
    cnt[t] = 0; cnt[t + 512] = 0;
    __syncthreads();

    if (fits) {
        for (int blk = t; blk < NBLK; blk += 512) {
            int len = runlen[blk];
            int srcp = locoff[blk * NBUCK + b];
            int dstp = runpos[blk];
            for (int i = 0; i < len; ++i) stage[dstp + i] = binned[srcp + i];
        }
        __syncthreads();
        for (int k = t; k < total; k += 512) {
            int p = stage[k];
            int key = ((p & 255) << 2) | ((p >> 8) / QDIV);
            atomicAdd(&cnt[key], 1);
        }
    } else {   // overflow fallback (statistically never)
        for (int blk = t; blk < NBLK; blk += 512) {
            int len = runlen[blk];
            int srcp = locoff[blk * NBUCK + b];
            for (int i = 0; i < len; ++i) {
                int p = binned[srcp + i];
                int key = ((p & 255) << 2) | ((p >> 8) / QDIV);
                atomicAdd(&cnt[key], 1);
            }
        }
    }
    __syncthreads();

    // exclusive scan over 1024 keys (2 slots/thread Hillis-Steele)
    sc[t] = cnt[t]; sc[t + 512] = cnt[t + 512];
    __syncthreads();
#pragma unroll
    for (int o = 1; o < 1024; o <<= 1) {
        int a0 = (t >= o) ? sc[t - o] : 0;
        int a1 = (t + 512 >= o) ? sc[t + 512 - o] : 0;
        __syncthreads();
        sc[t] += a0; sc[t + 512] += a1;
        __syncthreads();
    }
#pragma unroll
    for (int slot = 0; slot < 2; ++slot) {
        int k = t + slot * 512;
        int excl = sc[k] - cnt[k];
        cur[k] = excl;
        int dl = k >> 2, q = k & 3;
        int n = b * BUCKET + dl;
        if (n < N_NODES) {
            rowseg[n * 4 + q] = beg + excl;
            if (q == 0)
                dinv[n] = rsqrtf((float)(cnt[k] + cnt[k + 1] + cnt[k + 2] + cnt[k + 3] + 1));
        }
    }
    if (b == NBUCK - 1 && t == 0) rowseg[(size_t)N_NODES * 4] = end;  // sentinel
    __syncthreads();

    if (fits) {
        for (int k = t; k < total; k += 512) {
            int p = stage[k];
            int key = ((p & 255) << 2) | ((p >> 8) / QDIV);
            int pos = atomicAdd(&cur[key], 1);
            csr_src[beg + pos] = p >> 8;
        }
    } else {
        for (int blk = t; blk < NBLK; blk += 512) {
            int len = runlen[blk];
            int srcp = locoff[blk * NBUCK + b];
            for (int i = 0; i < len; ++i) {
                int p = binned[srcp + i];
                int key = ((p & 255) << 2) | ((p >> 8) / QDIV);
                int pos = atomicAdd(&cur[key], 1);
                csr_src[beg + pos] = p >> 8;
            }
        }
    }
}

// ================= dense helpers =================
__device__ inline void store_half8(__half* p, const float* v) {
    __half2 h[4];
#pragma unroll
    for (int i = 0; i < 4; ++i)
        h[i] = __floats2half2_rn(v[2 * i], v[2 * i + 1]);
    *(float4*)p = *(float4*)h;
}

__device__ inline void acc_half8(float* acc, float4 raw) {
    __half2* hp = (__half2*)&raw;
#pragma unroll
    for (int i = 0; i < 4; ++i) {
        float2 f = __half22float2(hp[i]);
        acc[2 * i]     += f.x;
        acc[2 * i + 1] += f.y;
    }
}

// t = relu(x@Wfc1 + bfc1); g = half( dinv * (t@Wc1) )
__global__ __launch_bounds__(256) void k_fc1_conv1(
        const float* __restrict__ x,
        const float* __restrict__ Wfc1, const float* __restrict__ bfc1,
        const float* __restrict__ Wc1, const float* __restrict__ dinv,
        __half* __restrict__ g) {
    __shared__ float  sWf[128];
    __shared__ float  sbf[32];
    __shared__ float4 sW[256];
    if (threadIdx.x < 128) sWf[threadIdx.x] = Wfc1[threadIdx.x];
    if (threadIdx.x < 32)  sbf[threadIdx.x] = bfc1[threadIdx.x];
    sW[threadIdx.x] = ((const float4*)Wc1)[threadIdx.x];
    __syncthreads();

    int n = blockIdx.x * 256 + threadIdx.x;
    if (n >= N_NODES) return;

    float4 xin = *(const float4*)(x + (size_t)n * 4);
    float t[32];
#pragma unroll
    for (int j = 0; j < 32; ++j) {
        float a = fmaf(xin.x, sWf[j], sbf[j]);
        a = fmaf(xin.y, sWf[32 + j], a);
        a = fmaf(xin.z, sWf[64 + j], a);
        a = fmaf(xin.w, sWf[96 + j], a);
        t[j] = fmaxf(a, 0.0f);
    }
    float o[32];
#pragma unroll
    for (int j = 0; j < 32; ++j) o[j] = 0.f;
#pragma unroll
    for (int k = 0; k < 32; ++k) {
        float a = t[k];
#pragma unroll
        for (int q = 0; q < 8; ++q) {
            float4 w = sW[k * 8 + q];
            o[q * 4 + 0] = fmaf(a, w.x, o[q * 4 + 0]);
            o[q * 4 + 1] = fmaf(a, w.y, o[q * 4 + 1]);
            o[q * 4 + 2] = fmaf(a, w.z, o[q * 4 + 2]);
            o[q * 4 + 3] = fmaf(a, w.w, o[q * 4 + 3]);
        }
    }
    float dv = dinv[n];
#pragma unroll
    for (int j = 0; j < 32; ++j) o[j] *= dv;
    __half* gp = g + (size_t)n * 32;
    store_half8(gp,      o);
    store_half8(gp + 8,  o + 8);
    store_half8(gp + 16, o + 16);
    store_half8(gp + 24, o + 24);
}

// ---- edge-segment accumulate: software-pipelined (prefetch next 4 indices) ----
__device__ inline void gather_seg(int beg, int end, const int* __restrict__ csr_src,
                                  const __half* __restrict__ gin, int sub, float* acc) {
    int k = beg;
    int stop = beg + ((end - beg) & ~3);
    if (k < stop) {
        int s0 = csr_src[k], s1 = csr_src[k + 1];
        int s2 = csr_src[k + 2], s3 = csr_src[k + 3];
        k += 4;
        while (k < stop) {
            float4 r0 = *(const float4*)(gin + (size_t)s0 * 32 + sub * 8);
            float4 r1 = *(const float4*)(gin + (size_t)s1 * 32 + sub * 8);
            float4 r2 = *(const float4*)(gin + (size_t)s2 * 32 + sub * 8);
            float4 r3 = *(const float4*)(gin + (size_t)s3 * 32 + sub * 8);
            s0 = csr_src[k]; s1 = csr_src[k + 1];
            s2 = csr_src[k + 2]; s3 = csr_src[k + 3];
            acc_half8(acc, r0); acc_half8(acc, r1);
            acc_half8(acc, r2); acc_half8(acc, r3);
            k += 4;
        }
        float4 r0 = *(const float4*)(gin + (size_t)s0 * 32 + sub * 8);
        float4 r1 = *(const float4*)(gin + (size_t)s1 * 32 + sub * 8);
        float4 r2 = *(const float4*)(gin + (size_t)s2 * 32 + sub * 8);
        float4 r3 = *(const float4*)(gin + (size_t)s3 * 32 + sub * 8);
        acc_half8(acc, r0); acc_half8(acc, r1);
        acc_half8(acc, r2); acc_half8(acc, r3);
    }
    for (; k < end; ++k) {
        int s = csr_src[k];
        float4 r = *(const float4*)(gin + (size_t)s * 32 + sub * 8);
        acc_half8(acc, r);
    }
}

// ---- 4-phase soft gather + mid MLP: 4 threads/node, 64 nodes/block ----
__global__ __launch_bounds__(256) void k_gather_mid(
        const int* __restrict__ rowseg,
        const int* __restrict__ csr_src, const __half* __restrict__ gin,
        const float* __restrict__ dinv,
        const float* __restrict__ b, const float* __restrict__ W,
        __half* __restrict__ gout) {
    __shared__ float sS[64 * 33];
    __shared__ float sW[1024];
    __shared__ float sb[32];
    for (int i = threadIdx.x; i < 1024; i += 256) sW[i] = W[i];
    if (threadIdx.x < 32) sb[threadIdx.x] = b[threadIdx.x];

    int nl = threadIdx.x >> 2;
    int sub = threadIdx.x & 3;
    int n = blockIdx.x * 64 + nl;
    float acc[8];
    if (n < N_NODES) {
        float4 self = *(const float4*)(gin + (size_t)n * 32 + sub * 8);
        {
            __half2* hp = (__half2*)&self;
#pragma unroll
            for (int i = 0; i < 4; ++i) {
                float2 f = __half22float2(hp[i]);
                acc[2 * i] = f.x;
                acc[2 * i + 1] = f.y;
            }
        }
        int4 seg = *(const int4*)(rowseg + (size_t)n * 4);
        int segend = rowseg[(size_t)n * 4 + 4];          // next start / sentinel
        gather_seg(seg.x, seg.y, csr_src, gin, sub, acc);   // quad 0
        gather_seg(seg.y, seg.z, csr_src, gin, sub, acc);   // quad 1
        gather_seg(seg.z, seg.w, csr_src, gin, sub, acc);   // quad 2
        gather_seg(seg.w, segend, csr_src, gin, sub, acc);  // quad 3
#pragma unroll
        for (int i = 0; i < 8; ++i) sS[nl * 33 + sub * 8 + i] = acc[i];
    }
    __syncthreads();

    if (n >= N_NODES) return;
    float dv = dinv[n];
    float t[32];
#pragma unroll
    for (int kk = 0; kk < 32; ++kk)
        t[kk] = fmaxf(fmaf(dv, sS[nl * 33 + kk], sb[kk]), 0.0f);
    float o[8];
#pragma unroll
    for (int j = 0; j < 8; ++j) o[j] = 0.f;
#pragma unroll
    for (int kk = 0; kk < 32; ++kk) {
        float a = t[kk];
#pragma unroll
        for (int j = 0; j < 8; ++j)
            o[j] = fmaf(a, sW[kk * 32 + sub * 8 + j], o[j]);
    }
#pragma unroll
    for (int j = 0; j < 8; ++j) o[j] *= dv;
    store_half8(gout + (size_t)n * 32 + sub * 8, o);
}

// ---- 4-phase soft gather + final layer ----
__global__ __launch_bounds__(256) void k_gather_out(
        const int* __restrict__ rowseg,
        const int* __restrict__ csr_src, const __half* __restrict__ gin,
        const float* __restrict__ dinv,
        const float* __restrict__ bc3, const float* __restrict__ Wfc2,
        const float* __restrict__ bfc2, float* __restrict__ out) {
    __shared__ float sS[64 * 33];
    __shared__ float sW[96];
    __shared__ float sb[32];
    __shared__ float sb2[3];
    if (threadIdx.x < 96) sW[threadIdx.x] = Wfc2[threadIdx.x];
    if (threadIdx.x < 32) sb[threadIdx.x] = bc3[threadIdx.x];
    if (threadIdx.x < 3)  sb2[threadIdx.x] = bfc2[threadIdx.x];

    int nl = threadIdx.x >> 2;
    int sub = threadIdx.x & 3;
    int n = blockIdx.x * 64 + nl;
    float acc[8];
    if (n < N_NODES) {
        float4 self = *(const float4*)(gin + (size_t)n * 32 + sub * 8);
        {
            __half2* hp = (__half2*)&self;
#pragma unroll
            for (int i = 0; i < 4; ++i) {
                float2 f = __half22float2(hp[i]);
                acc[2 * i] = f.x;
                acc[2 * i + 1] = f.y;
            }
        }
        int4 seg = *(const int4*)(rowseg + (size_t)n * 4);
        int segend = rowseg[(size_t)n * 4 + 4];
        gather_seg(seg.x, seg.y, csr_src, gin, sub, acc);
        gather_seg(seg.y, seg.z, csr_src, gin, sub, acc);
        gather_seg(seg.z, seg.w, csr_src, gin, sub, acc);
        gather_seg(seg.w, segend, csr_src, gin, sub, acc);
#pragma unroll
        for (int i = 0; i < 8; ++i) sS[nl * 33 + sub * 8 + i] = acc[i];
    }
    __syncthreads();

    if (n >= N_NODES || sub != 0) return;
    float dv = dinv[n];
    float t[32];
#pragma unroll
    for (int kk = 0; kk < 32; ++kk)
        t[kk] = fmaxf(fmaf(dv, sS[nl * 33 + kk], sb[kk]), 0.0f);
    float o0 = sb2[0], o1 = sb2[1], o2 = sb2[2];
#pragma unroll
    for (int kk = 0; kk < 32; ++kk) {
        o0 = fmaf(t[kk], sW[kk * 3 + 0], o0);
        o1 = fmaf(t[kk], sW[kk * 3 + 1], o1);
        o2 = fmaf(t[kk], sW[kk * 3 + 2], o2);
    }
    out[(size_t)n * 3 + 0] = o0;
    out[(size_t)n * 3 + 1] = o1;
    out[(size_t)n * 3 + 2] = o2;
}

extern "C" void kernel_launch(void* const* d_in, const int* in_sizes, int n_in,
                              void* d_out, int out_size, void* d_ws, size_t ws_size,
                              hipStream_t stream) {
    const float* x    = (const float*)d_in[0];
    const int*   ei   = (const int*)d_in[1];
    const float* Wfc1 = (const float*)d_in[2];
    const float* bfc1 = (const float*)d_in[3];
    const float* Wc1  = (const float*)d_in[4];
    const float* bc1  = (const float*)d_in[5];
    const float* Wc2  = (const float*)d_in[6];
    const float* bc2  = (const float*)d_in[7];
    const float* Wc3  = (const float*)d_in[8];
    const float* bc3  = (const float*)d_in[9];
    const float* Wfc2 = (const float*)d_in[10];
    const float* bfc2 = (const float*)d_in[11];
    float* out = (float*)d_out;

    char* ws = (char*)d_ws;
    const size_t grow = (size_t)N_NODES * 32 * sizeof(__half);   // 6.4 MB
    size_t off = 0;
    __half* gA     = (__half*)(ws + off); off += grow;
    __half* gB     = (__half*)(ws + off); off += grow;
    int*   binned  = (int*)  (ws + off); off += (size_t)NBLK * CHUNK * sizeof(int);
    int*   csr_src = (int*)  (ws + off); off += (size_t)N_EDGES * sizeof(int);
    float* dinv    = (float*)(ws + off); off += (size_t)N_NODES * sizeof(float);
    int*   rowseg  = (int*)  (ws + off); off += ((size_t)N_NODES * 4 + 16) * sizeof(int);
    int*   blkbin  = (int*)  (ws + off); off += (size_t)NBUCK * NBLK * sizeof(int);
    int*   blkpos  = (int*)  (ws + off); off += (size_t)NBUCK * NBLK * sizeof(int);
    int*   locoff  = (int*)  (ws + off); off += (size_t)NBLK * NBUCK * sizeof(int);
    int*   bintot  = (int*)  (ws + off); off += (size_t)NBUCK * sizeof(int);
    int*   binoff  = (int*)  (ws + off); off += (size_t)(NBUCK + 1) * sizeof(int);

    const int nb_wave = (NBUCK + 3) / 4;              // 98
    const int nb_n = (N_NODES + 255) / 256;           // 391
    const int nb_f = (N_NODES * 4 + 255) / 256;       // 1563 (4 thr/node)

    k_binfill<<<NBLK, 256, 0, stream>>>(ei, binned, blkbin, locoff);
    k_binwave<<<nb_wave, 256, 0, stream>>>(blkbin, bintot, blkpos);
    k_binscan<<<1, 512, 0, stream>>>(bintot, binoff);
    k_sortdeg<<<NBUCK, 512, 0, stream>>>(binned, blkbin, blkpos, locoff, binoff,
                                         csr_src, rowseg, dinv);

    k_fc1_conv1<<<nb_n, 256, 0, stream>>>(x, Wfc1, bfc1, Wc1, dinv, gA);
    k_gather_mid<<<nb_f, 256, 0, stream>>>(rowseg, csr_src, gA, dinv, bc1, Wc2, gB);
    k_gather_mid<<<nb_f, 256, 0, stream>>>(rowseg, csr_src, gB, dinv, bc2, Wc3, gA);
    k_gather_out<<<nb_f, 256, 0, stream>>>(rowseg, csr_src, gA, dinv, bc3, Wfc2, bfc2, out);
}